// Round 2
// baseline (8843.257 us; speedup 1.0000x reference)
//
#include <hip/hip_runtime.h>
#include <cfloat>
#include <cstdint>

#define NPTS 8192
#define NBROWS 16384

__device__ __forceinline__ unsigned fkey(float f) {
  unsigned u = __float_as_uint(f);
  return (u & 0x80000000u) ? ~u : (u | 0x80000000u);
}
__device__ __forceinline__ float fdecode(unsigned k) {
  unsigned u = (k & 0x80000000u) ? (k ^ 0x80000000u) : ~k;
  return __uint_as_float(u);
}

// ---------------- squared norms of x (C=3) ----------------
__global__ __launch_bounds__(256) void sqx_kernel(const float* __restrict__ x,
                                                  float* __restrict__ sq) {
  int r = blockIdx.x * 256 + threadIdx.x;
  const float* xp = x + (size_t)r * 3;
  sq[r] = fmaf(xp[2], xp[2], fmaf(xp[1], xp[1], xp[0] * xp[0]));
}

// ---------------- knn(k=32) on x + local covariance -> feat12 ----------------
__global__ __launch_bounds__(256) void knn32_cov_kernel(const float* __restrict__ x,
                                                        const float* __restrict__ sqx,
                                                        float* __restrict__ feat) {
  __shared__ __align__(16) float stage[4 * 128 * 4];
  __shared__ float ld[256 * 33];
  __shared__ unsigned short li[256 * 33];
  __shared__ unsigned short mergedIdx[64 * 32];

  const int t = threadIdx.x;
  const int r = t & 63, sub = t >> 6;
  const int rowBase = blockIdx.x * 64;
  const int batchBase = rowBase & ~(NPTS - 1);
  const int gRow = rowBase + r;

  const float xi0 = x[(size_t)gRow * 3 + 0];
  const float xi1 = x[(size_t)gRow * 3 + 1];
  const float xi2 = x[(size_t)gRow * 3 + 2];
  const float sqi = sqx[gRow];

  const int base = t * 33;
  for (int p = 0; p < 32; ++p) { ld[base + p] = FLT_MAX; li[base + p] = 65535; }
  float cmax = FLT_MAX;
  int cmaxi = 65535;

  for (int round = 0; round < 16; ++round) {
    __syncthreads();
    #pragma unroll
    for (int u = 0; u < 2; ++u) {
      int pp = t + 256 * u;
      int s = pp >> 7, jj = pp & 127;
      int j = s * 2048 + round * 128 + jj;
      const float* xp = x + (size_t)(batchBase + j) * 3;
      float4 w;
      w.x = xp[0]; w.y = xp[1]; w.z = xp[2];
      w.w = sqx[batchBase + j];
      *(float4*)(stage + pp * 4) = w;
    }
    __syncthreads();
    const float* st = stage + sub * 128 * 4;
    for (int jj = 0; jj < 128; ++jj) {
      float4 w = *(const float4*)(st + jj * 4);
      float dot = fmaf(xi2, w.z, fmaf(xi1, w.y, xi0 * w.x));
      float d = sqi + w.w - 2.0f * dot;
      int j = sub * 2048 + round * 128 + jj;
      if (d < cmax || (d == cmax && j < cmaxi)) {
        int p = 31;
        while (p > 0) {
          float pd = ld[base + p - 1];
          int pi = (int)li[base + p - 1];
          if (d < pd || (d == pd && j < pi)) {
            ld[base + p] = pd; li[base + p] = (unsigned short)pi; --p;
          } else break;
        }
        ld[base + p] = d; li[base + p] = (unsigned short)j;
        cmax = ld[base + 31]; cmaxi = (int)li[base + 31];
      }
    }
  }
  __syncthreads();
  if (t < 64) {
    int ps[4] = {0, 0, 0, 0};
    for (int z = 0; z < 32; ++z) {
      float bd = FLT_MAX; int bi = 0x7FFFFFFF; int bs = 0;
      #pragma unroll
      for (int s = 0; s < 4; ++s) {
        if (ps[s] < 32) {
          int bb = (t + 64 * s) * 33 + ps[s];
          float d = ld[bb]; int i = (int)li[bb];
          if (d < bd || (d == bd && i < bi)) { bd = d; bi = i; bs = s; }
        }
      }
      mergedIdx[t * 32 + z] = (unsigned short)bi;
      ps[bs]++;
    }
  }
  __syncthreads();
  if (t < 64) {
    float sx = 0.f, sy = 0.f, sz = 0.f;
    for (int z = 0; z < 32; ++z) {
      const float* xp = x + (size_t)(batchBase + (int)mergedIdx[t * 32 + z]) * 3;
      sx += xp[0]; sy += xp[1]; sz += xp[2];
    }
    const float m0 = sx * (1.f / 32.f), m1 = sy * (1.f / 32.f), m2 = sz * (1.f / 32.f);
    float c00 = 0, c01 = 0, c02 = 0, c11 = 0, c12 = 0, c22 = 0;
    for (int z = 0; z < 32; ++z) {
      const float* xp = x + (size_t)(batchBase + (int)mergedIdx[t * 32 + z]) * 3;
      float a0 = xp[0] - m0, a1 = xp[1] - m1, a2 = xp[2] - m2;
      c00 = fmaf(a0, a0, c00); c01 = fmaf(a0, a1, c01); c02 = fmaf(a0, a2, c02);
      c11 = fmaf(a1, a1, c11); c12 = fmaf(a1, a2, c12); c22 = fmaf(a2, a2, c22);
    }
    const float inv = 1.f / 32.f;
    float* fp = feat + (size_t)(rowBase + t) * 12;
    fp[0] = xi0; fp[1] = xi1; fp[2] = xi2;
    fp[3] = c00 * inv; fp[4] = c01 * inv; fp[5] = c02 * inv;
    fp[6] = c01 * inv; fp[7] = c11 * inv; fp[8] = c12 * inv;
    fp[9] = c02 * inv; fp[10] = c12 * inv; fp[11] = c22 * inv;
  }
}

// ---------------- feat12 @ W1 -> y (+ per-block BN partials, deterministic) ----------------
__global__ __launch_bounds__(64) void mm12_64_kernel(const float* __restrict__ feat,
                                                     const float* __restrict__ W,
                                                     float* __restrict__ y,
                                                     float* __restrict__ psum,
                                                     float* __restrict__ psq) {
  __shared__ __align__(16) float Ws[12 * 64];
  const int t = threadIdx.x;
  for (int u = t; u < 192; u += 64) ((float4*)Ws)[u] = ((const float4*)W)[u];
  __syncthreads();
  const int row = blockIdx.x * 64 + t;
  float in[12];
  {
    const float4* fp = (const float4*)(feat + (size_t)row * 12);
    float4 a = fp[0], b = fp[1], c = fp[2];
    in[0] = a.x; in[1] = a.y; in[2] = a.z; in[3] = a.w;
    in[4] = b.x; in[5] = b.y; in[6] = b.z; in[7] = b.w;
    in[8] = c.x; in[9] = c.y; in[10] = c.z; in[11] = c.w;
  }
  float acc[64];
  #pragma unroll
  for (int o = 0; o < 64; ++o) acc[o] = 0.f;
  #pragma unroll
  for (int i = 0; i < 12; ++i) {
    const float xi = in[i];
    #pragma unroll
    for (int og = 0; og < 16; ++og) {
      float4 w4 = *(const float4*)(Ws + i * 64 + og * 4);
      acc[og * 4 + 0] = fmaf(xi, w4.x, acc[og * 4 + 0]);
      acc[og * 4 + 1] = fmaf(xi, w4.y, acc[og * 4 + 1]);
      acc[og * 4 + 2] = fmaf(xi, w4.z, acc[og * 4 + 2]);
      acc[og * 4 + 3] = fmaf(xi, w4.w, acc[og * 4 + 3]);
    }
  }
  float4* yp = (float4*)(y + (size_t)row * 64);
  #pragma unroll
  for (int og = 0; og < 16; ++og)
    yp[og] = make_float4(acc[og * 4 + 0], acc[og * 4 + 1], acc[og * 4 + 2], acc[og * 4 + 3]);
  #pragma unroll 1
  for (int o = 0; o < 64; ++o) {
    float s = acc[o], q = acc[o] * acc[o];
    #pragma unroll
    for (int m = 1; m < 64; m <<= 1) { s += __shfl_xor(s, m); q += __shfl_xor(q, m); }
    if (t == 0) { psum[blockIdx.x * 64 + o] = s; psq[blockIdx.x * 64 + o] = q; }
  }
}

// ---------------- generic 64->OUT matmul, optional fused BN+ReLU; per-block partials ----------------
template <int OUT, bool BNRELU>
__global__ __launch_bounds__(64) void mm64_kernel(const float* __restrict__ src,
                                                  const float* __restrict__ W,
                                                  const float* __restrict__ scale,
                                                  const float* __restrict__ shift,
                                                  float* __restrict__ y,
                                                  float* __restrict__ psum,
                                                  float* __restrict__ psq) {
  __shared__ __align__(16) float Ws[64 * OUT];
  const int t = threadIdx.x;
  for (int u = t; u < 16 * OUT; u += 64) ((float4*)Ws)[u] = ((const float4*)W)[u];
  __syncthreads();
  const int row = blockIdx.x * 64 + t;
  float in[64];
  {
    const float4* sp = (const float4*)(src + (size_t)row * 64);
    #pragma unroll
    for (int u = 0; u < 16; ++u) {
      float4 v = sp[u];
      if (BNRELU) {
        v.x = fmaxf(fmaf(v.x, scale[u * 4 + 0], shift[u * 4 + 0]), 0.f);
        v.y = fmaxf(fmaf(v.y, scale[u * 4 + 1], shift[u * 4 + 1]), 0.f);
        v.z = fmaxf(fmaf(v.z, scale[u * 4 + 2], shift[u * 4 + 2]), 0.f);
        v.w = fmaxf(fmaf(v.w, scale[u * 4 + 3], shift[u * 4 + 3]), 0.f);
      }
      in[u * 4 + 0] = v.x; in[u * 4 + 1] = v.y; in[u * 4 + 2] = v.z; in[u * 4 + 3] = v.w;
    }
  }
  for (int half = 0; half < OUT / 64; ++half) {
    float acc[64];
    #pragma unroll
    for (int o = 0; o < 64; ++o) acc[o] = 0.f;
    #pragma unroll 4
    for (int i = 0; i < 64; ++i) {
      const float xi = in[i];
      #pragma unroll
      for (int og = 0; og < 16; ++og) {
        float4 w4 = *(const float4*)(Ws + i * OUT + half * 64 + og * 4);
        acc[og * 4 + 0] = fmaf(xi, w4.x, acc[og * 4 + 0]);
        acc[og * 4 + 1] = fmaf(xi, w4.y, acc[og * 4 + 1]);
        acc[og * 4 + 2] = fmaf(xi, w4.z, acc[og * 4 + 2]);
        acc[og * 4 + 3] = fmaf(xi, w4.w, acc[og * 4 + 3]);
      }
    }
    float4* yp = (float4*)(y + (size_t)row * OUT + half * 64);
    #pragma unroll
    for (int og = 0; og < 16; ++og)
      yp[og] = make_float4(acc[og * 4 + 0], acc[og * 4 + 1], acc[og * 4 + 2], acc[og * 4 + 3]);
    #pragma unroll 1
    for (int o = 0; o < 64; ++o) {
      float s = acc[o], q = acc[o] * acc[o];
      #pragma unroll
      for (int m = 1; m < 64; m <<= 1) { s += __shfl_xor(s, m); q += __shfl_xor(q, m); }
      if (t == 0) {
        psum[blockIdx.x * OUT + half * 64 + o] = s;
        psq[blockIdx.x * OUT + half * 64 + o] = q;
      }
    }
  }
}

// ---------------- deterministic BN finalize from 256 per-block partials ----------------
template <int C>
__global__ void finP_kernel(const float* __restrict__ psum, const float* __restrict__ psq,
                            const float* __restrict__ g, const float* __restrict__ b,
                            float* __restrict__ scale, float* __restrict__ shift) {
  int c = threadIdx.x;
  float s = 0.f, q = 0.f;
  for (int bb = 0; bb < 256; ++bb) { s += psum[bb * C + c]; q += psq[bb * C + c]; }
  float m = s * (1.f / 16384.f);
  float v = q * (1.f / 16384.f) - m * m;
  float sc = g[c] * rsqrtf(v + 1e-5f);
  scale[c] = sc;
  shift[c] = b[c] - m * sc;
}

// ---------------- apply BN + activation, compute row sq-norm ----------------
template <int C, bool LEAKY>
__global__ __launch_bounds__(256) void apply_kernel(const float* __restrict__ yraw,
                                                    const float* __restrict__ scale,
                                                    const float* __restrict__ shift,
                                                    float* __restrict__ hout,
                                                    float* __restrict__ sqout) {
  const int row = blockIdx.x * 256 + threadIdx.x;
  const float4* sp = (const float4*)(yraw + (size_t)row * C);
  float4* dp = (float4*)(hout + (size_t)row * C);
  float sq = 0.f;
  #pragma unroll
  for (int u = 0; u < C / 4; ++u) {
    float4 v = sp[u];
    float4 o;
    o.x = fmaf(v.x, scale[u * 4 + 0], shift[u * 4 + 0]);
    o.y = fmaf(v.y, scale[u * 4 + 1], shift[u * 4 + 1]);
    o.z = fmaf(v.z, scale[u * 4 + 2], shift[u * 4 + 2]);
    o.w = fmaf(v.w, scale[u * 4 + 3], shift[u * 4 + 3]);
    if (LEAKY) {
      o.x = o.x > 0.f ? o.x : 0.01f * o.x;
      o.y = o.y > 0.f ? o.y : 0.01f * o.y;
      o.z = o.z > 0.f ? o.z : 0.01f * o.z;
      o.w = o.w > 0.f ? o.w : 0.01f * o.w;
    } else {
      o.x = fmaxf(o.x, 0.f); o.y = fmaxf(o.y, 0.f);
      o.z = fmaxf(o.z, 0.f); o.w = fmaxf(o.w, 0.f);
    }
    sq = fmaf(o.x, o.x, sq); sq = fmaf(o.y, o.y, sq);
    sq = fmaf(o.z, o.z, sq); sq = fmaf(o.w, o.w, sq);
    dp[u] = o;
  }
  sqout[row] = sq;
}

// ---------------- knn(k=8) on C-dim features + fused gather-max ----------------
template <int C>
__global__ __launch_bounds__(256) void knn8_kernel(const float* __restrict__ h,
                                                   const float* __restrict__ sqh,
                                                   float* __restrict__ nout) {
  static_assert(C == 64 || C == 128, "C");
  __shared__ __align__(16) float As[C * 32];
  __shared__ __align__(16) float Bs[C * 64];
  __shared__ float sqA[32];
  __shared__ float sqB[64];
  __shared__ float dls[32 * 65];
  __shared__ int idxL[32 * 8];

  const int t = threadIdx.x;
  const int rowBase = blockIdx.x * 32;
  const int batchBase = rowBase & ~(NPTS - 1);
  const int tx = t & 15, ty = t >> 4;
  const int r = t & 31, sub = t >> 5;

  {
    const int ar = t & 31;
    const int k0 = (t >> 5) * (C / 8);
    const float* src = h + (size_t)(rowBase + ar) * C + k0;
    #pragma unroll
    for (int kk = 0; kk < C / 8; kk += 4) {
      float4 v = *(const float4*)(src + kk);
      As[(k0 + kk + 0) * 32 + ar] = v.x;
      As[(k0 + kk + 1) * 32 + ar] = v.y;
      As[(k0 + kk + 2) * 32 + ar] = v.z;
      As[(k0 + kk + 3) * 32 + ar] = v.w;
    }
    if (t < 32) sqA[t] = sqh[rowBase + t];
  }

  float td[8]; int ti[8];
  #pragma unroll
  for (int q = 0; q < 8; ++q) { td[q] = FLT_MAX; ti[q] = 0x7FFFFFFF; }

  for (int tile = 0; tile < NPTS / 64; ++tile) {
    const int colBase = tile * 64;
    __syncthreads();
    {
      const int bc = t & 63;
      const int k0 = (t >> 6) * (C / 4);
      const float* src = h + (size_t)(batchBase + colBase + bc) * C + k0;
      #pragma unroll
      for (int kk = 0; kk < C / 4; kk += 4) {
        float4 v = *(const float4*)(src + kk);
        Bs[(k0 + kk + 0) * 64 + bc] = v.x;
        Bs[(k0 + kk + 1) * 64 + bc] = v.y;
        Bs[(k0 + kk + 2) * 64 + bc] = v.z;
        Bs[(k0 + kk + 3) * 64 + bc] = v.w;
      }
      if (t < 64) sqB[t] = sqh[batchBase + colBase + t];
    }
    __syncthreads();
    float acc[8];
    #pragma unroll
    for (int q = 0; q < 8; ++q) acc[q] = 0.f;
    #pragma unroll 4
    for (int k = 0; k < C; ++k) {
      float2 a2 = *(const float2*)(As + k * 32 + ty * 2);
      float4 b4 = *(const float4*)(Bs + k * 64 + tx * 4);
      acc[0] = fmaf(a2.x, b4.x, acc[0]);
      acc[1] = fmaf(a2.x, b4.y, acc[1]);
      acc[2] = fmaf(a2.x, b4.z, acc[2]);
      acc[3] = fmaf(a2.x, b4.w, acc[3]);
      acc[4] = fmaf(a2.y, b4.x, acc[4]);
      acc[5] = fmaf(a2.y, b4.y, acc[5]);
      acc[6] = fmaf(a2.y, b4.z, acc[6]);
      acc[7] = fmaf(a2.y, b4.w, acc[7]);
    }
    #pragma unroll
    for (int q = 0; q < 2; ++q) {
      const int rr = ty * 2 + q;
      const float sa = sqA[rr];
      #pragma unroll
      for (int p = 0; p < 4; ++p)
        dls[rr * 65 + tx * 4 + p] = sa + sqB[tx * 4 + p] - 2.0f * acc[q * 4 + p];
    }
    __syncthreads();
    for (int cc = 0; cc < 8; ++cc) {
      const int c = sub * 8 + cc;
      const float d = dls[r * 65 + c];
      const int j = colBase + c;
      if (d < td[7] || (d == td[7] && j < ti[7])) {
        bool placed = false;
        #pragma unroll
        for (int q = 7; q >= 1; --q) {
          bool sh = !placed && (d < td[q - 1] || (d == td[q - 1] && j < ti[q - 1]));
          if (sh) { td[q] = td[q - 1]; ti[q] = ti[q - 1]; }
          else if (!placed) { td[q] = d; ti[q] = j; placed = true; }
        }
        if (!placed) { td[0] = d; ti[0] = j; }
      }
    }
  }
  __syncthreads();
  float* md = dls;
  int* mi = (int*)Bs;
  #pragma unroll
  for (int q = 0; q < 8; ++q) {
    md[(r * 8 + sub) * 8 + q] = td[q];
    mi[(r * 8 + sub) * 8 + q] = ti[q];
  }
  __syncthreads();
  if (t < 32) {
    int ps[8] = {0, 0, 0, 0, 0, 0, 0, 0};
    for (int z = 0; z < 8; ++z) {
      float bd = FLT_MAX; int bi = 0x7FFFFFFF; int bs = 0;
      #pragma unroll
      for (int s = 0; s < 8; ++s) {
        if (ps[s] < 8) {
          int bb = (t * 8 + s) * 8 + ps[s];
          float d = md[bb]; int i = mi[bb];
          if (d < bd || (d == bd && i < bi)) { bd = d; bi = i; bs = s; }
        }
      }
      idxL[t * 8 + z] = bi;
      ps[bs]++;
    }
  }
  __syncthreads();
  {
    const int gr = t >> 3;
    const int cg = t & 7;
    constexpr int CW = C / 8;
    float mx[CW];
    #pragma unroll
    for (int u = 0; u < CW; ++u) mx[u] = -FLT_MAX;
    for (int q = 0; q < 8; ++q) {
      const float* src = h + (size_t)(batchBase + idxL[gr * 8 + q]) * C + cg * CW;
      #pragma unroll
      for (int u = 0; u < CW; u += 4) {
        float4 v = *(const float4*)(src + u);
        mx[u + 0] = fmaxf(mx[u + 0], v.x);
        mx[u + 1] = fmaxf(mx[u + 1], v.y);
        mx[u + 2] = fmaxf(mx[u + 2], v.z);
        mx[u + 3] = fmaxf(mx[u + 3], v.w);
      }
    }
    float* dst = nout + (size_t)(rowBase + gr) * C + cg * CW;
    #pragma unroll
    for (int u = 0; u < CW; u += 4)
      *(float4*)(dst + u) = make_float4(mx[u + 0], mx[u + 1], mx[u + 2], mx[u + 3]);
  }
}

// ---------------- n2[16384,128] @ gW2[128,1024]: deterministic stats partials + atomicMax ----------------
__global__ __launch_bounds__(256) void mmE_kernel(const float* __restrict__ n2,
                                                  const float* __restrict__ W,
                                                  float* __restrict__ psum,
                                                  float* __restrict__ psq,
                                                  unsigned* __restrict__ gmax) {
  __shared__ __align__(16) float As[64 * 64];
  __shared__ __align__(16) float Bs[64 * 64];
  __shared__ float sP[16 * 64];
  __shared__ float qP[16 * 64];
  __shared__ float mP[16 * 64];
  const int t = threadIdx.x;
  const int rowStripe = blockIdx.x >> 4;
  const int colStripe = blockIdx.x & 15;
  const int rowBase = rowStripe * 64;
  const int colBase = colStripe * 64;
  const int batch = rowBase >> 13;
  const int tx = t & 15, ty = t >> 4;

  float acc[16];
  #pragma unroll
  for (int q = 0; q < 16; ++q) acc[q] = 0.f;

  for (int kh = 0; kh < 2; ++kh) {
    __syncthreads();
    {
      const int ar = t & 63;
      const int k0 = (t >> 6) * 16;
      const float* src = n2 + (size_t)(rowBase + ar) * 128 + kh * 64 + k0;
      #pragma unroll
      for (int kk = 0; kk < 16; kk += 4) {
        float4 v = *(const float4*)(src + kk);
        As[(k0 + kk + 0) * 64 + ar] = v.x;
        As[(k0 + kk + 1) * 64 + ar] = v.y;
        As[(k0 + kk + 2) * 64 + ar] = v.z;
        As[(k0 + kk + 3) * 64 + ar] = v.w;
      }
    }
    {
      #pragma unroll
      for (int z = 0; z < 4; ++z) {
        int u = t + 256 * z;
        int k = u >> 4, c4 = u & 15;
        float4 v = *(const float4*)(W + (size_t)(kh * 64 + k) * 1024 + colBase + c4 * 4);
        *(float4*)(Bs + k * 64 + c4 * 4) = v;
      }
    }
    __syncthreads();
    #pragma unroll 4
    for (int k = 0; k < 64; ++k) {
      float4 a4 = *(const float4*)(As + k * 64 + ty * 4);
      float4 b4 = *(const float4*)(Bs + k * 64 + tx * 4);
      acc[0] = fmaf(a4.x, b4.x, acc[0]);   acc[1] = fmaf(a4.x, b4.y, acc[1]);
      acc[2] = fmaf(a4.x, b4.z, acc[2]);   acc[3] = fmaf(a4.x, b4.w, acc[3]);
      acc[4] = fmaf(a4.y, b4.x, acc[4]);   acc[5] = fmaf(a4.y, b4.y, acc[5]);
      acc[6] = fmaf(a4.y, b4.z, acc[6]);   acc[7] = fmaf(a4.y, b4.w, acc[7]);
      acc[8] = fmaf(a4.z, b4.x, acc[8]);   acc[9] = fmaf(a4.z, b4.y, acc[9]);
      acc[10] = fmaf(a4.z, b4.z, acc[10]); acc[11] = fmaf(a4.z, b4.w, acc[11]);
      acc[12] = fmaf(a4.w, b4.x, acc[12]); acc[13] = fmaf(a4.w, b4.y, acc[13]);
      acc[14] = fmaf(a4.w, b4.z, acc[14]); acc[15] = fmaf(a4.w, b4.w, acc[15]);
    }
  }
  // deterministic per-thread partials over this thread's 4 rows
  #pragma unroll
  for (int p = 0; p < 4; ++p) {
    float s = 0.f, q = 0.f, m = -FLT_MAX;
    #pragma unroll
    for (int qq = 0; qq < 4; ++qq) {
      float v = acc[qq * 4 + p];
      s += v; q = fmaf(v, v, q); m = fmaxf(m, v);
    }
    sP[ty * 64 + tx * 4 + p] = s;
    qP[ty * 64 + tx * 4 + p] = q;
    mP[ty * 64 + tx * 4 + p] = m;
  }
  __syncthreads();
  if (t < 64) {
    float s = 0.f, q = 0.f, m = -FLT_MAX;
    #pragma unroll
    for (int u = 0; u < 16; ++u) {
      s += sP[u * 64 + t];
      q += qP[u * 64 + t];
      m = fmaxf(m, mP[u * 64 + t]);
    }
    psum[rowStripe * 1024 + colBase + t] = s;
    psq [rowStripe * 1024 + colBase + t] = q;
    atomicMax(&gmax[batch * 1024 + colBase + t], fkey(m));   // uint max: order-independent
  }
}

// ---------------- BN4 finalize (deterministic stripe sum) + leaky on pooled max ----------------
__global__ void poolbn_kernel(const float* __restrict__ psumE, const float* __restrict__ psqE,
                              const unsigned* __restrict__ gmax,
                              const float* __restrict__ gg2, const float* __restrict__ gb2,
                              float* __restrict__ fpool) {
  int c = threadIdx.x;
  float s = 0.f, q = 0.f;
  for (int bb = 0; bb < 256; ++bb) { s += psumE[bb * 1024 + c]; q += psqE[bb * 1024 + c]; }
  float m = s * (1.f / 16384.f);
  float v = q * (1.f / 16384.f) - m * m;
  float sc = gg2[c] * rsqrtf(v + 1e-5f);
  float sh = gb2[c] - m * sc;
  #pragma unroll
  for (int b = 0; b < 2; ++b) {
    float raw = fdecode(gmax[b * 1024 + c]);
    float t = fmaf(raw, sc, sh);
    fpool[b * 1024 + c] = t > 0.f ? t : 0.01f * t;
  }
}

// ---------------- fpool @ W4 + BN over 2 samples + relu -> out ----------------
__global__ __launch_bounds__(64) void final_kernel(const float* __restrict__ fpool,
                                                   const float* __restrict__ W4,
                                                   const float* __restrict__ g4,
                                                   const float* __restrict__ b4f,
                                                   float* __restrict__ out) {
  const int o = blockIdx.x * 64 + threadIdx.x;
  float a0 = 0.f, a1 = 0.f;
  for (int c = 0; c < 1024; ++c) {
    float w = W4[(size_t)c * 512 + o];
    a0 = fmaf(fpool[c], w, a0);
    a1 = fmaf(fpool[1024 + c], w, a1);
  }
  float m = 0.5f * (a0 + a1);
  float d0 = a0 - m, d1 = a1 - m;
  float v = 0.5f * (d0 * d0 + d1 * d1);
  float r = rsqrtf(v + 1e-5f);
  float o0 = fmaf(d0 * r, g4[o], b4f[o]);
  float o1 = fmaf(d1 * r, g4[o], b4f[o]);
  out[o] = fmaxf(o0, 0.f);
  out[512 + o] = fmaxf(o1, 0.f);
}

extern "C" void kernel_launch(void* const* d_in, const int* in_sizes, int n_in,
                              void* d_out, int out_size, void* d_ws, size_t ws_size,
                              hipStream_t stream) {
  (void)in_sizes; (void)n_in; (void)out_size; (void)ws_size;
  const float* x   = (const float*)d_in[0];
  const float* W1  = (const float*)d_in[1];
  const float* g1  = (const float*)d_in[2];
  const float* b1  = (const float*)d_in[3];
  const float* W2  = (const float*)d_in[4];
  const float* g2  = (const float*)d_in[5];
  const float* b2  = (const float*)d_in[6];
  const float* W3  = (const float*)d_in[7];
  const float* g3  = (const float*)d_in[8];
  const float* b3  = (const float*)d_in[9];
  const float* gW1 = (const float*)d_in[10];
  const float* gg1 = (const float*)d_in[11];
  const float* gb1 = (const float*)d_in[12];
  const float* gW2 = (const float*)d_in[13];
  const float* gg2 = (const float*)d_in[14];
  const float* gb2 = (const float*)d_in[15];
  const float* W4  = (const float*)d_in[16];
  const float* g4  = (const float*)d_in[17];
  const float* b4  = (const float*)d_in[18];
  float* out = (float*)d_out;
  float* ws = (float*)d_ws;

  float* sqx  = ws;                  // 16384
  float* feat = sqx + 16384;         // 196608
  float* yA   = feat + 196608;       // 1048576
  float* yB   = yA + 1048576;        // 1048576
  float* h3   = yB + 1048576;        // 1048576
  float* sqh  = h3 + 1048576;        // 16384
  float* yg1  = sqh + 16384;         // 2097152
  float* hg1  = yg1 + 2097152;       // 2097152
  float* sqg  = hg1 + 2097152;       // 16384
  float* st   = sqg + 16384;         // stats / small buffers

  unsigned* gmax = (unsigned*)(st);          // 2048 uints
  float* scale0 = st + 2048;  float* shift0 = st + 2112;
  float* scale1 = st + 2176;  float* shift1 = st + 2240;
  float* scale2 = st + 2304;  float* shift2 = st + 2368;
  float* scale3 = st + 2432;  float* shift3 = st + 2560;
  float* fpool  = st + 2688;                 // 2048
  float* p1s    = st + 4736;                 // 256*64
  float* p1q    = p1s + 16384;               // 256*64  (ends at st+37504)

  // partials aliased into dead buffers:
  float* p2s = feat;             float* p2q = feat + 16384;        // L2: feat dead after mm12_64
  float* p3s = feat + 32768;     float* p3q = feat + 49152;        // L3
  float* p4s = yB;               float* p4q = yB + 32768;          // gW1 layer: yB dead after L3
  float* pEs = h3;               float* pEq = h3 + 262144;         // mmE: h3 dead after knn8<64>

  float* n1 = yA;   // raw y3 consumed by apply before knn8<64> writes here
  float* n2 = yg1;  // raw yg1 consumed by apply before knn8<128> writes here

  hipMemsetAsync(gmax, 0, 2048 * sizeof(unsigned), stream);
  sqx_kernel<<<64, 256, 0, stream>>>(x, sqx);
  knn32_cov_kernel<<<256, 256, 0, stream>>>(x, sqx, feat);
  mm12_64_kernel<<<256, 64, 0, stream>>>(feat, W1, yA, p1s, p1q);
  finP_kernel<64><<<1, 64, 0, stream>>>(p1s, p1q, g1, b1, scale0, shift0);
  mm64_kernel<64, true><<<256, 64, 0, stream>>>(yA, W2, scale0, shift0, yB, p2s, p2q);
  finP_kernel<64><<<1, 64, 0, stream>>>(p2s, p2q, g2, b2, scale1, shift1);
  mm64_kernel<64, true><<<256, 64, 0, stream>>>(yB, W3, scale1, shift1, yA, p3s, p3q);
  finP_kernel<64><<<1, 64, 0, stream>>>(p3s, p3q, g3, b3, scale2, shift2);
  apply_kernel<64, false><<<64, 256, 0, stream>>>(yA, scale2, shift2, h3, sqh);
  knn8_kernel<64><<<512, 256, 0, stream>>>(h3, sqh, n1);
  mm64_kernel<128, false><<<256, 64, 0, stream>>>(n1, gW1, scale0, shift0, yg1, p4s, p4q);
  finP_kernel<128><<<1, 128, 0, stream>>>(p4s, p4q, gg1, gb1, scale3, shift3);
  apply_kernel<128, true><<<64, 256, 0, stream>>>(yg1, scale3, shift3, hg1, sqg);
  knn8_kernel<128><<<512, 256, 0, stream>>>(hg1, sqg, n2);
  mmE_kernel<<<4096, 256, 0, stream>>>(n2, gW2, pEs, pEq, gmax);
  poolbn_kernel<<<1, 1024, 0, stream>>>(pEs, pEq, gmax, gg2, gb2, fpool);
  final_kernel<<<8, 64, 0, stream>>>(fpool, W4, g4, b4, out);
}

// Round 3
// 2999.075 us; speedup vs baseline: 2.9487x; 2.9487x over previous
//
#include <hip/hip_runtime.h>
#include <cfloat>
#include <cstdint>

#define NPTS 8192
#define NBROWS 16384

__device__ __forceinline__ unsigned fkey(float f) {
  unsigned u = __float_as_uint(f);
  return (u & 0x80000000u) ? ~u : (u | 0x80000000u);
}
__device__ __forceinline__ float fdecode(unsigned k) {
  unsigned u = (k & 0x80000000u) ? (k ^ 0x80000000u) : ~k;
  return __uint_as_float(u);
}

// Branchless sorted-insert into ascending register list of packed u64 keys.
// All levels are independent (read old values only) -> high ILP, no divergence.
template <int K>
__device__ __forceinline__ void chain_insert(unsigned long long (&kk)[K],
                                             unsigned long long key) {
  #pragma unroll
  for (int q = K - 1; q >= 1; --q) {
    bool cm1 = key < kk[q - 1];
    bool cq  = key < kk[q];
    kk[q] = cm1 ? kk[q - 1] : (cq ? key : kk[q]);
  }
  kk[0] = (key < kk[0]) ? key : kk[0];
}

// ---------------- squared norms of x (C=3) ----------------
__global__ __launch_bounds__(256) void sqx_kernel(const float* __restrict__ x,
                                                  float* __restrict__ sq) {
  int r = blockIdx.x * 256 + threadIdx.x;
  const float* xp = x + (size_t)r * 3;
  sq[r] = fmaf(xp[2], xp[2], fmaf(xp[1], xp[1], xp[0] * xp[0]));
}

// ---------------- knn(k=32) on x + local covariance -> feat12 ----------------
// 256 thr = 32 rows x 8 subs; each sub scans 1024 candidates (8 rounds x 128)
// top-32 per (row,sub) kept in registers as packed u64 keys; one LDS merge at end.
__global__ __launch_bounds__(256) void knn32_cov_kernel(const float* __restrict__ x,
                                                        const float* __restrict__ sqx,
                                                        float* __restrict__ feat) {
  // union region: during scan: stage[1024] float4 (16KB)
  // after scan:   mlK u32[256*32] (32KB) | mlI u16[256*32] (16KB) | mergedIdx u16[1024] (2KB)
  __shared__ __align__(16) float smem[12800];   // 51.2 KB
  float4* stage4 = (float4*)smem;
  unsigned* mlK = (unsigned*)smem;                       // [256][32]
  unsigned short* mlI = (unsigned short*)(smem + 8192);  // [256][32]
  unsigned short* mergedIdx = (unsigned short*)(smem + 12288); // [32][32]

  const int t = threadIdx.x;
  const int r = t & 31, sub = t >> 5;
  const int rowBase = blockIdx.x * 32;
  const int batchBase = rowBase & ~(NPTS - 1);
  const int gRow = rowBase + r;

  const float xi0 = x[(size_t)gRow * 3 + 0];
  const float xi1 = x[(size_t)gRow * 3 + 1];
  const float xi2 = x[(size_t)gRow * 3 + 2];
  const float sqi = sqx[gRow];

  unsigned long long kk[32];
  #pragma unroll
  for (int q = 0; q < 32; ++q) kk[q] = ~0ULL;

  for (int round = 0; round < 8; ++round) {
    __syncthreads();
    // stage 8 subs x 128 candidates
    #pragma unroll
    for (int u = 0; u < 4; ++u) {
      int pp = t + 256 * u;            // 0..1023
      int s = pp >> 7, jj = pp & 127;
      int j = s * 1024 + round * 128 + jj;
      const float* xp = x + (size_t)(batchBase + j) * 3;
      float4 w;
      w.x = xp[0]; w.y = xp[1]; w.z = xp[2];
      w.w = sqx[batchBase + j];
      stage4[pp] = w;
    }
    __syncthreads();
    const float4* st = stage4 + sub * 128;
    for (int jj = 0; jj < 128; ++jj) {
      float4 w = st[jj];
      float dot = fmaf(xi2, w.z, fmaf(xi1, w.y, xi0 * w.x));
      float d = sqi + w.w - 2.0f * dot;
      int j = sub * 1024 + round * 128 + jj;
      unsigned long long key = ((unsigned long long)fkey(d) << 16) | (unsigned)j;
      chain_insert<32>(kk, key);
    }
  }
  __syncthreads();   // stage dead; write merge lists (aliased region)
  #pragma unroll
  for (int q = 0; q < 32; ++q) {
    mlK[t * 32 + q] = (unsigned)(kk[q] >> 16);
    mlI[t * 32 + q] = (unsigned short)(kk[q] & 0xFFFFULL);
  }
  __syncthreads();
  if (t < 32) {
    // 8-way merge of sorted lists (lists for row t live at threads s*32+t)
    int ps[8] = {0, 0, 0, 0, 0, 0, 0, 0};
    for (int z = 0; z < 32; ++z) {
      unsigned bk = 0xFFFFFFFFu; unsigned bi = 0xFFFFu; int bs = 0;
      #pragma unroll
      for (int s = 0; s < 8; ++s) {
        int off = (s * 32 + t) * 32 + ps[s];
        unsigned k = mlK[off];
        unsigned i = mlI[off];
        if (k < bk || (k == bk && i < bi)) { bk = k; bi = i; bs = s; }
      }
      mergedIdx[t * 32 + z] = (unsigned short)bi;
      #pragma unroll
      for (int s = 0; s < 8; ++s) ps[s] += (s == bs);
    }
  }
  __syncthreads();
  if (t < 32) {
    float sx = 0.f, sy = 0.f, sz = 0.f;
    for (int z = 0; z < 32; ++z) {
      const float* xp = x + (size_t)(batchBase + (int)mergedIdx[t * 32 + z]) * 3;
      sx += xp[0]; sy += xp[1]; sz += xp[2];
    }
    const float m0 = sx * (1.f / 32.f), m1 = sy * (1.f / 32.f), m2 = sz * (1.f / 32.f);
    float c00 = 0, c01 = 0, c02 = 0, c11 = 0, c12 = 0, c22 = 0;
    for (int z = 0; z < 32; ++z) {
      const float* xp = x + (size_t)(batchBase + (int)mergedIdx[t * 32 + z]) * 3;
      float a0 = xp[0] - m0, a1 = xp[1] - m1, a2 = xp[2] - m2;
      c00 = fmaf(a0, a0, c00); c01 = fmaf(a0, a1, c01); c02 = fmaf(a0, a2, c02);
      c11 = fmaf(a1, a1, c11); c12 = fmaf(a1, a2, c12); c22 = fmaf(a2, a2, c22);
    }
    const float inv = 1.f / 32.f;
    float* fp = feat + (size_t)(rowBase + t) * 12;
    fp[0] = xi0; fp[1] = xi1; fp[2] = xi2;
    fp[3] = c00 * inv; fp[4] = c01 * inv; fp[5] = c02 * inv;
    fp[6] = c01 * inv; fp[7] = c11 * inv; fp[8] = c12 * inv;
    fp[9] = c02 * inv; fp[10] = c12 * inv; fp[11] = c22 * inv;
  }
}

// ---------------- feat12 @ W1 -> y (+ per-block BN partials, deterministic) ----------------
__global__ __launch_bounds__(64) void mm12_64_kernel(const float* __restrict__ feat,
                                                     const float* __restrict__ W,
                                                     float* __restrict__ y,
                                                     float* __restrict__ psum,
                                                     float* __restrict__ psq) {
  __shared__ __align__(16) float Ws[12 * 64];
  const int t = threadIdx.x;
  for (int u = t; u < 192; u += 64) ((float4*)Ws)[u] = ((const float4*)W)[u];
  __syncthreads();
  const int row = blockIdx.x * 64 + t;
  float in[12];
  {
    const float4* fp = (const float4*)(feat + (size_t)row * 12);
    float4 a = fp[0], b = fp[1], c = fp[2];
    in[0] = a.x; in[1] = a.y; in[2] = a.z; in[3] = a.w;
    in[4] = b.x; in[5] = b.y; in[6] = b.z; in[7] = b.w;
    in[8] = c.x; in[9] = c.y; in[10] = c.z; in[11] = c.w;
  }
  float acc[64];
  #pragma unroll
  for (int o = 0; o < 64; ++o) acc[o] = 0.f;
  #pragma unroll
  for (int i = 0; i < 12; ++i) {
    const float xi = in[i];
    #pragma unroll
    for (int og = 0; og < 16; ++og) {
      float4 w4 = *(const float4*)(Ws + i * 64 + og * 4);
      acc[og * 4 + 0] = fmaf(xi, w4.x, acc[og * 4 + 0]);
      acc[og * 4 + 1] = fmaf(xi, w4.y, acc[og * 4 + 1]);
      acc[og * 4 + 2] = fmaf(xi, w4.z, acc[og * 4 + 2]);
      acc[og * 4 + 3] = fmaf(xi, w4.w, acc[og * 4 + 3]);
    }
  }
  float4* yp = (float4*)(y + (size_t)row * 64);
  #pragma unroll
  for (int og = 0; og < 16; ++og)
    yp[og] = make_float4(acc[og * 4 + 0], acc[og * 4 + 1], acc[og * 4 + 2], acc[og * 4 + 3]);
  #pragma unroll 1
  for (int o = 0; o < 64; ++o) {
    float s = acc[o], q = acc[o] * acc[o];
    #pragma unroll
    for (int m = 1; m < 64; m <<= 1) { s += __shfl_xor(s, m); q += __shfl_xor(q, m); }
    if (t == 0) { psum[blockIdx.x * 64 + o] = s; psq[blockIdx.x * 64 + o] = q; }
  }
}

// ---------------- generic 64->OUT matmul, optional fused BN+ReLU; per-block partials ----------------
template <int OUT, bool BNRELU>
__global__ __launch_bounds__(64) void mm64_kernel(const float* __restrict__ src,
                                                  const float* __restrict__ W,
                                                  const float* __restrict__ scale,
                                                  const float* __restrict__ shift,
                                                  float* __restrict__ y,
                                                  float* __restrict__ psum,
                                                  float* __restrict__ psq) {
  __shared__ __align__(16) float Ws[64 * OUT];
  const int t = threadIdx.x;
  for (int u = t; u < 16 * OUT; u += 64) ((float4*)Ws)[u] = ((const float4*)W)[u];
  __syncthreads();
  const int row = blockIdx.x * 64 + t;
  float in[64];
  {
    const float4* sp = (const float4*)(src + (size_t)row * 64);
    #pragma unroll
    for (int u = 0; u < 16; ++u) {
      float4 v = sp[u];
      if (BNRELU) {
        v.x = fmaxf(fmaf(v.x, scale[u * 4 + 0], shift[u * 4 + 0]), 0.f);
        v.y = fmaxf(fmaf(v.y, scale[u * 4 + 1], shift[u * 4 + 1]), 0.f);
        v.z = fmaxf(fmaf(v.z, scale[u * 4 + 2], shift[u * 4 + 2]), 0.f);
        v.w = fmaxf(fmaf(v.w, scale[u * 4 + 3], shift[u * 4 + 3]), 0.f);
      }
      in[u * 4 + 0] = v.x; in[u * 4 + 1] = v.y; in[u * 4 + 2] = v.z; in[u * 4 + 3] = v.w;
    }
  }
  for (int half = 0; half < OUT / 64; ++half) {
    float acc[64];
    #pragma unroll
    for (int o = 0; o < 64; ++o) acc[o] = 0.f;
    #pragma unroll 4
    for (int i = 0; i < 64; ++i) {
      const float xi = in[i];
      #pragma unroll
      for (int og = 0; og < 16; ++og) {
        float4 w4 = *(const float4*)(Ws + i * OUT + half * 64 + og * 4);
        acc[og * 4 + 0] = fmaf(xi, w4.x, acc[og * 4 + 0]);
        acc[og * 4 + 1] = fmaf(xi, w4.y, acc[og * 4 + 1]);
        acc[og * 4 + 2] = fmaf(xi, w4.z, acc[og * 4 + 2]);
        acc[og * 4 + 3] = fmaf(xi, w4.w, acc[og * 4 + 3]);
      }
    }
    float4* yp = (float4*)(y + (size_t)row * OUT + half * 64);
    #pragma unroll
    for (int og = 0; og < 16; ++og)
      yp[og] = make_float4(acc[og * 4 + 0], acc[og * 4 + 1], acc[og * 4 + 2], acc[og * 4 + 3]);
    #pragma unroll 1
    for (int o = 0; o < 64; ++o) {
      float s = acc[o], q = acc[o] * acc[o];
      #pragma unroll
      for (int m = 1; m < 64; m <<= 1) { s += __shfl_xor(s, m); q += __shfl_xor(q, m); }
      if (t == 0) {
        psum[blockIdx.x * OUT + half * 64 + o] = s;
        psq[blockIdx.x * OUT + half * 64 + o] = q;
      }
    }
  }
}

// ---------------- deterministic BN finalize from 256 per-block partials ----------------
template <int C>
__global__ void finP_kernel(const float* __restrict__ psum, const float* __restrict__ psq,
                            const float* __restrict__ g, const float* __restrict__ b,
                            float* __restrict__ scale, float* __restrict__ shift) {
  int c = threadIdx.x;
  float s = 0.f, q = 0.f;
  for (int bb = 0; bb < 256; ++bb) { s += psum[bb * C + c]; q += psq[bb * C + c]; }
  float m = s * (1.f / 16384.f);
  float v = q * (1.f / 16384.f) - m * m;
  float sc = g[c] * rsqrtf(v + 1e-5f);
  scale[c] = sc;
  shift[c] = b[c] - m * sc;
}

// ---------------- apply BN + activation, compute row sq-norm ----------------
template <int C, bool LEAKY>
__global__ __launch_bounds__(256) void apply_kernel(const float* __restrict__ yraw,
                                                    const float* __restrict__ scale,
                                                    const float* __restrict__ shift,
                                                    float* __restrict__ hout,
                                                    float* __restrict__ sqout) {
  const int row = blockIdx.x * 256 + threadIdx.x;
  const float4* sp = (const float4*)(yraw + (size_t)row * C);
  float4* dp = (float4*)(hout + (size_t)row * C);
  float sq = 0.f;
  #pragma unroll
  for (int u = 0; u < C / 4; ++u) {
    float4 v = sp[u];
    float4 o;
    o.x = fmaf(v.x, scale[u * 4 + 0], shift[u * 4 + 0]);
    o.y = fmaf(v.y, scale[u * 4 + 1], shift[u * 4 + 1]);
    o.z = fmaf(v.z, scale[u * 4 + 2], shift[u * 4 + 2]);
    o.w = fmaf(v.w, scale[u * 4 + 3], shift[u * 4 + 3]);
    if (LEAKY) {
      o.x = o.x > 0.f ? o.x : 0.01f * o.x;
      o.y = o.y > 0.f ? o.y : 0.01f * o.y;
      o.z = o.z > 0.f ? o.z : 0.01f * o.z;
      o.w = o.w > 0.f ? o.w : 0.01f * o.w;
    } else {
      o.x = fmaxf(o.x, 0.f); o.y = fmaxf(o.y, 0.f);
      o.z = fmaxf(o.z, 0.f); o.w = fmaxf(o.w, 0.f);
    }
    sq = fmaf(o.x, o.x, sq); sq = fmaf(o.y, o.y, sq);
    sq = fmaf(o.z, o.z, sq); sq = fmaf(o.w, o.w, sq);
    dp[u] = o;
  }
  sqout[row] = sq;
}

// ---------------- knn(k=8) distance GEMM + register top-8 -> per-(row,half) partial lists ----
// 256 thr (16x16), 64 rows/block, 4x4 register micro-tile, 64-col tiles.
// grid = 256 row-groups x 2 column halves (4096 cols each).
template <int C>
__global__ __launch_bounds__(256) void knn8_kernel(const float* __restrict__ h,
                                                   const float* __restrict__ sqh,
                                                   unsigned long long* __restrict__ plist) {
  static_assert(C == 64 || C == 128, "C");
  constexpr int SMEMF = (C * 64 + C * 68) > 16384 ? (C * 64 + C * 68) : 16384;
  __shared__ __align__(16) float smem[SMEMF];
  __shared__ float sqAs[64];
  __shared__ float sqBs[64];
  float* As = smem;            // [k][64]
  float* Bs = smem + C * 64;   // [k][68] padded

  const int t = threadIdx.x;
  const int rg = blockIdx.x >> 1, half = blockIdx.x & 1;
  const int rowBase = rg * 64;
  const int batchBase = rowBase & ~(NPTS - 1);
  const int tx = t & 15, ty = t >> 4;

  // stage A once (transpose to [k][row])
  {
    const int ar = t & 63;
    const int k0 = (t >> 6) * (C / 4);
    const float* src = h + (size_t)(rowBase + ar) * C + k0;
    #pragma unroll
    for (int kk = 0; kk < C / 4; kk += 4) {
      float4 v = *(const float4*)(src + kk);
      As[(k0 + kk + 0) * 64 + ar] = v.x;
      As[(k0 + kk + 1) * 64 + ar] = v.y;
      As[(k0 + kk + 2) * 64 + ar] = v.z;
      As[(k0 + kk + 3) * 64 + ar] = v.w;
    }
    if (t < 64) sqAs[t] = sqh[rowBase + t];
  }

  unsigned long long L[4][8];
  #pragma unroll
  for (int q = 0; q < 4; ++q)
    #pragma unroll
    for (int z = 0; z < 8; ++z) L[q][z] = ~0ULL;

  for (int tile = 0; tile < 64; ++tile) {
    const int colBase = half * 4096 + tile * 64;
    __syncthreads();
    // stage B (transpose to [k][col], pad 68)
    {
      const int bc = t & 63;
      const int k0 = (t >> 6) * (C / 4);
      const float* src = h + (size_t)(batchBase + colBase + bc) * C + k0;
      #pragma unroll
      for (int kk = 0; kk < C / 4; kk += 4) {
        float4 v = *(const float4*)(src + kk);
        Bs[(k0 + kk + 0) * 68 + bc] = v.x;
        Bs[(k0 + kk + 1) * 68 + bc] = v.y;
        Bs[(k0 + kk + 2) * 68 + bc] = v.z;
        Bs[(k0 + kk + 3) * 68 + bc] = v.w;
      }
      if (t < 64) sqBs[t] = sqh[batchBase + colBase + t];
    }
    __syncthreads();
    float acc[16];
    #pragma unroll
    for (int q = 0; q < 16; ++q) acc[q] = 0.f;
    #pragma unroll 4
    for (int k = 0; k < C; ++k) {
      float4 a4 = *(const float4*)(As + k * 64 + ty * 4);
      float4 b4 = *(const float4*)(Bs + k * 68 + tx * 4);
      acc[0] = fmaf(a4.x, b4.x, acc[0]);   acc[1] = fmaf(a4.x, b4.y, acc[1]);
      acc[2] = fmaf(a4.x, b4.z, acc[2]);   acc[3] = fmaf(a4.x, b4.w, acc[3]);
      acc[4] = fmaf(a4.y, b4.x, acc[4]);   acc[5] = fmaf(a4.y, b4.y, acc[5]);
      acc[6] = fmaf(a4.y, b4.z, acc[6]);   acc[7] = fmaf(a4.y, b4.w, acc[7]);
      acc[8] = fmaf(a4.z, b4.x, acc[8]);   acc[9] = fmaf(a4.z, b4.y, acc[9]);
      acc[10] = fmaf(a4.z, b4.z, acc[10]); acc[11] = fmaf(a4.z, b4.w, acc[11]);
      acc[12] = fmaf(a4.w, b4.x, acc[12]); acc[13] = fmaf(a4.w, b4.y, acc[13]);
      acc[14] = fmaf(a4.w, b4.z, acc[14]); acc[15] = fmaf(a4.w, b4.w, acc[15]);
    }
    #pragma unroll
    for (int q = 0; q < 4; ++q) {
      const float sa = sqAs[ty * 4 + q];
      #pragma unroll
      for (int p = 0; p < 4; ++p) {
        float d = sa + sqBs[tx * 4 + p] - 2.0f * acc[q * 4 + p];
        int j = colBase + tx * 4 + p;
        unsigned long long key = ((unsigned long long)fkey(d) << 16) | (unsigned)j;
        chain_insert<8>(L[q], key);
      }
    }
  }
  __syncthreads();   // staging dead; alias smem as merge buffer [64 rows][16 tx][8]
  unsigned long long* mb = (unsigned long long*)smem;
  #pragma unroll
  for (int q = 0; q < 4; ++q)
    #pragma unroll
    for (int z = 0; z < 8; ++z)
      mb[((ty * 4 + q) * 16 + tx) * 8 + z] = L[q][z];
  __syncthreads();
  if (t < 64) {
    int ps[16];
    #pragma unroll
    for (int s = 0; s < 16; ++s) ps[s] = 0;
    unsigned long long outk[8];
    for (int z = 0; z < 8; ++z) {
      unsigned long long best = ~0ULL; int bs = 0;
      #pragma unroll
      for (int s = 0; s < 16; ++s) {
        unsigned long long v = mb[(t * 16 + s) * 8 + ps[s]];
        if (v < best) { best = v; bs = s; }
      }
      outk[z] = best;
      #pragma unroll
      for (int s = 0; s < 16; ++s) ps[s] += (s == bs);
    }
    unsigned long long* dst = plist + ((size_t)(rowBase + t) * 2 + half) * 8;
    #pragma unroll
    for (int z = 0; z < 8; ++z) dst[z] = outk[z];
  }
}

// ---------------- merge 2 half-lists -> top-8 idx; fused gather-max ----------------
// block 256 = 4 rows x 64 lanes
template <int C>
__global__ __launch_bounds__(256) void knn8mg_kernel(const unsigned long long* __restrict__ plist,
                                                     const float* __restrict__ h,
                                                     float* __restrict__ nout) {
  const int row = blockIdx.x * 4 + (threadIdx.x >> 6);
  const int lane = threadIdx.x & 63;
  const int batchBase = row & ~(NPTS - 1);
  const unsigned long long* A = plist + (size_t)row * 16;
  unsigned long long kk[8];
  #pragma unroll
  for (int z = 0; z < 8; ++z) kk[z] = A[z];
  #pragma unroll
  for (int z = 0; z < 8; ++z) chain_insert<8>(kk, A[8 + z]);
  constexpr int PER = C / 64;
  float mx[PER];
  #pragma unroll
  for (int u = 0; u < PER; ++u) mx[u] = -FLT_MAX;
  #pragma unroll
  for (int z = 0; z < 8; ++z) {
    int idx = (int)(kk[z] & 0xFFFFULL);
    const float* src = h + (size_t)(batchBase + idx) * C;
    #pragma unroll
    for (int u = 0; u < PER; ++u)
      mx[u] = fmaxf(mx[u], src[lane + u * 64]);
  }
  float* dst = nout + (size_t)row * C;
  #pragma unroll
  for (int u = 0; u < PER; ++u) dst[lane + u * 64] = mx[u];
}

// ---------------- n2[16384,128] @ gW2[128,1024]: deterministic stats partials + atomicMax ----------------
__global__ __launch_bounds__(256) void mmE_kernel(const float* __restrict__ n2,
                                                  const float* __restrict__ W,
                                                  float* __restrict__ psum,
                                                  float* __restrict__ psq,
                                                  unsigned* __restrict__ gmax) {
  __shared__ __align__(16) float As[64 * 64];
  __shared__ __align__(16) float Bs[64 * 64];
  __shared__ float sP[16 * 64];
  __shared__ float qP[16 * 64];
  __shared__ float mP[16 * 64];
  const int t = threadIdx.x;
  const int rowStripe = blockIdx.x >> 4;
  const int colStripe = blockIdx.x & 15;
  const int rowBase = rowStripe * 64;
  const int colBase = colStripe * 64;
  const int batch = rowBase >> 13;
  const int tx = t & 15, ty = t >> 4;

  float acc[16];
  #pragma unroll
  for (int q = 0; q < 16; ++q) acc[q] = 0.f;

  for (int kh = 0; kh < 2; ++kh) {
    __syncthreads();
    {
      const int ar = t & 63;
      const int k0 = (t >> 6) * 16;
      const float* src = n2 + (size_t)(rowBase + ar) * 128 + kh * 64 + k0;
      #pragma unroll
      for (int kk = 0; kk < 16; kk += 4) {
        float4 v = *(const float4*)(src + kk);
        As[(k0 + kk + 0) * 64 + ar] = v.x;
        As[(k0 + kk + 1) * 64 + ar] = v.y;
        As[(k0 + kk + 2) * 64 + ar] = v.z;
        As[(k0 + kk + 3) * 64 + ar] = v.w;
      }
    }
    {
      #pragma unroll
      for (int z = 0; z < 4; ++z) {
        int u = t + 256 * z;
        int k = u >> 4, c4 = u & 15;
        float4 v = *(const float4*)(W + (size_t)(kh * 64 + k) * 1024 + colBase + c4 * 4);
        *(float4*)(Bs + k * 64 + c4 * 4) = v;
      }
    }
    __syncthreads();
    #pragma unroll 4
    for (int k = 0; k < 64; ++k) {
      float4 a4 = *(const float4*)(As + k * 64 + ty * 4);
      float4 b4 = *(const float4*)(Bs + k * 64 + tx * 4);
      acc[0] = fmaf(a4.x, b4.x, acc[0]);   acc[1] = fmaf(a4.x, b4.y, acc[1]);
      acc[2] = fmaf(a4.x, b4.z, acc[2]);   acc[3] = fmaf(a4.x, b4.w, acc[3]);
      acc[4] = fmaf(a4.y, b4.x, acc[4]);   acc[5] = fmaf(a4.y, b4.y, acc[5]);
      acc[6] = fmaf(a4.y, b4.z, acc[6]);   acc[7] = fmaf(a4.y, b4.w, acc[7]);
      acc[8] = fmaf(a4.z, b4.x, acc[8]);   acc[9] = fmaf(a4.z, b4.y, acc[9]);
      acc[10] = fmaf(a4.z, b4.z, acc[10]); acc[11] = fmaf(a4.z, b4.w, acc[11]);
      acc[12] = fmaf(a4.w, b4.x, acc[12]); acc[13] = fmaf(a4.w, b4.y, acc[13]);
      acc[14] = fmaf(a4.w, b4.z, acc[14]); acc[15] = fmaf(a4.w, b4.w, acc[15]);
    }
  }
  #pragma unroll
  for (int p = 0; p < 4; ++p) {
    float s = 0.f, q = 0.f, m = -FLT_MAX;
    #pragma unroll
    for (int qq = 0; qq < 4; ++qq) {
      float v = acc[qq * 4 + p];
      s += v; q = fmaf(v, v, q); m = fmaxf(m, v);
    }
    sP[ty * 64 + tx * 4 + p] = s;
    qP[ty * 64 + tx * 4 + p] = q;
    mP[ty * 64 + tx * 4 + p] = m;
  }
  __syncthreads();
  if (t < 64) {
    float s = 0.f, q = 0.f, m = -FLT_MAX;
    #pragma unroll
    for (int u = 0; u < 16; ++u) {
      s += sP[u * 64 + t];
      q += qP[u * 64 + t];
      m = fmaxf(m, mP[u * 64 + t]);
    }
    psum[rowStripe * 1024 + colBase + t] = s;
    psq [rowStripe * 1024 + colBase + t] = q;
    atomicMax(&gmax[batch * 1024 + colBase + t], fkey(m));
  }
}

// ---------------- BN4 finalize (deterministic stripe sum) + leaky on pooled max ----------------
__global__ void poolbn_kernel(const float* __restrict__ psumE, const float* __restrict__ psqE,
                              const unsigned* __restrict__ gmax,
                              const float* __restrict__ gg2, const float* __restrict__ gb2,
                              float* __restrict__ fpool) {
  int c = threadIdx.x;
  float s = 0.f, q = 0.f;
  for (int bb = 0; bb < 256; ++bb) { s += psumE[bb * 1024 + c]; q += psqE[bb * 1024 + c]; }
  float m = s * (1.f / 16384.f);
  float v = q * (1.f / 16384.f) - m * m;
  float sc = gg2[c] * rsqrtf(v + 1e-5f);
  float sh = gb2[c] - m * sc;
  #pragma unroll
  for (int b = 0; b < 2; ++b) {
    float raw = fdecode(gmax[b * 1024 + c]);
    float t = fmaf(raw, sc, sh);
    fpool[b * 1024 + c] = t > 0.f ? t : 0.01f * t;
  }
}

// ---------------- fpool @ W4 + BN over 2 samples + relu -> out ----------------
__global__ __launch_bounds__(64) void final_kernel(const float* __restrict__ fpool,
                                                   const float* __restrict__ W4,
                                                   const float* __restrict__ g4,
                                                   const float* __restrict__ b4f,
                                                   float* __restrict__ out) {
  const int o = blockIdx.x * 64 + threadIdx.x;
  float a0 = 0.f, a1 = 0.f;
  for (int c = 0; c < 1024; ++c) {
    float w = W4[(size_t)c * 512 + o];
    a0 = fmaf(fpool[c], w, a0);
    a1 = fmaf(fpool[1024 + c], w, a1);
  }
  float m = 0.5f * (a0 + a1);
  float d0 = a0 - m, d1 = a1 - m;
  float v = 0.5f * (d0 * d0 + d1 * d1);
  float r = rsqrtf(v + 1e-5f);
  float o0 = fmaf(d0 * r, g4[o], b4f[o]);
  float o1 = fmaf(d1 * r, g4[o], b4f[o]);
  out[o] = fmaxf(o0, 0.f);
  out[512 + o] = fmaxf(o1, 0.f);
}

extern "C" void kernel_launch(void* const* d_in, const int* in_sizes, int n_in,
                              void* d_out, int out_size, void* d_ws, size_t ws_size,
                              hipStream_t stream) {
  (void)in_sizes; (void)n_in; (void)out_size; (void)ws_size;
  const float* x   = (const float*)d_in[0];
  const float* W1  = (const float*)d_in[1];
  const float* g1  = (const float*)d_in[2];
  const float* b1  = (const float*)d_in[3];
  const float* W2  = (const float*)d_in[4];
  const float* g2  = (const float*)d_in[5];
  const float* b2  = (const float*)d_in[6];
  const float* W3  = (const float*)d_in[7];
  const float* g3  = (const float*)d_in[8];
  const float* b3  = (const float*)d_in[9];
  const float* gW1 = (const float*)d_in[10];
  const float* gg1 = (const float*)d_in[11];
  const float* gb1 = (const float*)d_in[12];
  const float* gW2 = (const float*)d_in[13];
  const float* gg2 = (const float*)d_in[14];
  const float* gb2 = (const float*)d_in[15];
  const float* W4  = (const float*)d_in[16];
  const float* g4  = (const float*)d_in[17];
  const float* b4  = (const float*)d_in[18];
  float* out = (float*)d_out;
  float* ws = (float*)d_ws;

  float* sqx  = ws;                  // 16384
  float* feat = sqx + 16384;         // 196608
  float* yA   = feat + 196608;       // 1048576
  float* yB   = yA + 1048576;        // 1048576
  float* h3   = yB + 1048576;        // 1048576
  float* sqh  = h3 + 1048576;        // 16384
  float* yg1  = sqh + 16384;         // 2097152
  float* hg1  = yg1 + 2097152;       // 2097152
  float* sqg  = hg1 + 2097152;       // 16384
  float* st   = sqg + 16384;         // stats / small buffers

  unsigned* gmax = (unsigned*)(st);          // 2048 uints
  float* scale0 = st + 2048;  float* shift0 = st + 2112;
  float* scale1 = st + 2176;  float* shift1 = st + 2240;
  float* scale2 = st + 2304;  float* shift2 = st + 2368;
  float* scale3 = st + 2432;  float* shift3 = st + 2560;
  float* fpool  = st + 2688;                 // 2048
  float* p1s    = st + 4736;                 // 256*64
  float* p1q    = p1s + 16384;               // 256*64

  // partials / lists aliased into dead buffers:
  float* p2s = feat;             float* p2q = feat + 16384;        // L2 stats
  float* p3s = feat + 32768;     float* p3q = feat + 49152;        // L3 stats
  float* p4s = yB;               float* p4q = yB + 32768;          // gW1 stats
  float* pEs = h3;               float* pEq = h3 + 262144;         // mmE stats
  unsigned long long* plist = (unsigned long long*)yB;             // knn8 partial lists (2MB)

  float* n1 = yA;   // raw y3 consumed by apply before knn8mg writes here
  float* n2 = yg1;  // raw yg1 consumed by apply before knn8mg writes here

  hipMemsetAsync(gmax, 0, 2048 * sizeof(unsigned), stream);
  sqx_kernel<<<64, 256, 0, stream>>>(x, sqx);
  knn32_cov_kernel<<<512, 256, 0, stream>>>(x, sqx, feat);
  mm12_64_kernel<<<256, 64, 0, stream>>>(feat, W1, yA, p1s, p1q);
  finP_kernel<64><<<1, 64, 0, stream>>>(p1s, p1q, g1, b1, scale0, shift0);
  mm64_kernel<64, true><<<256, 64, 0, stream>>>(yA, W2, scale0, shift0, yB, p2s, p2q);
  finP_kernel<64><<<1, 64, 0, stream>>>(p2s, p2q, g2, b2, scale1, shift1);
  mm64_kernel<64, true><<<256, 64, 0, stream>>>(yB, W3, scale1, shift1, yA, p3s, p3q);
  finP_kernel<64><<<1, 64, 0, stream>>>(p3s, p3q, g3, b3, scale2, shift2);
  apply_kernel<64, false><<<64, 256, 0, stream>>>(yA, scale2, shift2, h3, sqh);
  knn8_kernel<64><<<512, 256, 0, stream>>>(h3, sqh, plist);
  knn8mg_kernel<64><<<4096, 256, 0, stream>>>(plist, h3, n1);
  mm64_kernel<128, false><<<256, 64, 0, stream>>>(n1, gW1, scale0, shift0, yg1, p4s, p4q);
  finP_kernel<128><<<1, 128, 0, stream>>>(p4s, p4q, gg1, gb1, scale3, shift3);
  apply_kernel<128, true><<<64, 256, 0, stream>>>(yg1, scale3, shift3, hg1, sqg);
  knn8_kernel<128><<<512, 256, 0, stream>>>(hg1, sqg, plist);
  knn8mg_kernel<128><<<4096, 256, 0, stream>>>(plist, hg1, n2);
  mmE_kernel<<<4096, 256, 0, stream>>>(n2, gW2, pEs, pEq, gmax);
  poolbn_kernel<<<1, 1024, 0, stream>>>(pEs, pEq, gmax, gg2, gb2, fpool);
  final_kernel<<<8, 64, 0, stream>>>(fpool, W4, g4, b4, out);
}

// Round 4
// 1964.533 us; speedup vs baseline: 4.5015x; 1.5266x over previous
//
#include <hip/hip_runtime.h>
#include <cfloat>
#include <cstdint>

#define NPTS 8192
#define NBROWS 16384

typedef unsigned long long u64;

__device__ __forceinline__ unsigned fkey(float f) {
  unsigned u = __float_as_uint(f);
  return (u & 0x80000000u) ? ~u : (u | 0x80000000u);
}
__device__ __forceinline__ float fdecode(unsigned k) {
  unsigned u = (k & 0x80000000u) ? (k ^ 0x80000000u) : ~k;
  return __uint_as_float(u);
}

// Branchless sorted-insert into ascending register list of packed u64 keys.
template <int K>
__device__ __forceinline__ void chain_insert(u64 (&kk)[K], u64 key) {
  #pragma unroll
  for (int q = K - 1; q >= 1; --q) {
    bool cm1 = key < kk[q - 1];
    bool cq  = key < kk[q];
    kk[q] = cm1 ? kk[q - 1] : (cq ? key : kk[q]);
  }
  kk[0] = (key < kk[0]) ? key : kk[0];
}

// ---------------- squared norms of x (C=3) ----------------
__global__ __launch_bounds__(256) void sqx_kernel(const float* __restrict__ x,
                                                  float* __restrict__ sq) {
  int r = blockIdx.x * 256 + threadIdx.x;
  const float* xp = x + (size_t)r * 3;
  sq[r] = fmaf(xp[2], xp[2], fmaf(xp[1], xp[1], xp[0] * xp[0]));
}

// ---------------- knn(k=32) on x + local covariance -> feat12 ----------------
// block 512 = 32 rows x 16 subs; per sub 512 candidates (4 rounds x 128).
// Phase A: keys-only top-32 via min/max network (2 inst/level).
// Tournament: per-row 32nd-smallest key T over 16 sorted lists.
// Phase B: rescan, append (key,idx) with key<=T to per-row LDS buffer (<=40).
// Tail: exact top-32 by (key,idx) u64 chain; cov; feat12.
__global__ __launch_bounds__(512, 4) void knn32_cov_kernel(const float* __restrict__ x,
                                                           const float* __restrict__ sqx,
                                                           float* __restrict__ feat) {
  __shared__ __align__(16) unsigned char smem[78080];
  float4* stage4 = (float4*)smem;                        // [2048] 32KB (aliases keyArea)
  unsigned* keyArea = (unsigned*)smem;                   // [512*33] 67584B
  unsigned* Trow = (unsigned*)(smem + 67584);            // [32]
  unsigned* cnt  = (unsigned*)(smem + 67712);            // [32]
  u64* apb = (u64*)(smem + 67840);                       // [32*40] 10240B

  const int t = threadIdx.x;
  const int r = t & 31, sub = t >> 5;                    // sub 0..15
  const int rowBase = blockIdx.x * 32;
  const int batchBase = rowBase & ~(NPTS - 1);
  const int gRow = rowBase + r;

  const float xi0 = x[(size_t)gRow * 3 + 0];
  const float xi1 = x[(size_t)gRow * 3 + 1];
  const float xi2 = x[(size_t)gRow * 3 + 2];
  const float sqi = sqx[gRow];

  unsigned K[32];
  #pragma unroll
  for (int q = 0; q < 32; ++q) K[q] = 0xFFFFFFFFu;

  // ---- Phase A ----
  for (int round = 0; round < 4; ++round) {
    __syncthreads();
    #pragma unroll
    for (int u = 0; u < 4; ++u) {
      int pp = t + 512 * u;            // 0..2047
      int s = pp >> 7, jj = pp & 127;
      int j = s * 512 + round * 128 + jj;
      const float* xp = x + (size_t)(batchBase + j) * 3;
      float4 w;
      w.x = xp[0]; w.y = xp[1]; w.z = xp[2];
      w.w = sqx[batchBase + j];
      stage4[pp] = w;
    }
    __syncthreads();
    const float4* st = stage4 + sub * 128;
    for (int jj = 0; jj < 128; ++jj) {
      float4 w = st[jj];
      float dot = fmaf(xi2, w.z, fmaf(xi1, w.y, xi0 * w.x));
      float d = sqi + w.w - 2.0f * dot;
      unsigned key = fkey(d);
      #pragma unroll
      for (int q = 31; q >= 1; --q) K[q] = max(K[q - 1], min(key, K[q]));
      K[0] = min(key, K[0]);
    }
  }
  __syncthreads();     // stage dead; write sorted key lists
  {
    const int base = (sub * 32 + r) * 33;
    #pragma unroll
    for (int z = 0; z < 32; ++z) keyArea[base + z] = K[z];
  }
  __syncthreads();
  if (t < 32) {
    cnt[t] = 0u;
    unsigned P[16];
    #pragma unroll
    for (int s = 0; s < 16; ++s) P[s] = 0u;
    unsigned T = 0u;
    for (int step = 0; step < 32; ++step) {
      unsigned best = 0xFFFFFFFFu; int bs = 0;
      #pragma unroll
      for (int s = 0; s < 16; ++s) {
        unsigned v = keyArea[(s * 32 + t) * 33 + P[s]];
        if (v < best) { best = v; bs = s; }
      }
      T = best;
      #pragma unroll
      for (int s = 0; s < 16; ++s) P[s] += (s == bs);
    }
    Trow[t] = T;
  }
  __syncthreads();
  // ---- Phase B ----
  for (int round = 0; round < 4; ++round) {
    __syncthreads();
    #pragma unroll
    for (int u = 0; u < 4; ++u) {
      int pp = t + 512 * u;
      int s = pp >> 7, jj = pp & 127;
      int j = s * 512 + round * 128 + jj;
      const float* xp = x + (size_t)(batchBase + j) * 3;
      float4 w;
      w.x = xp[0]; w.y = xp[1]; w.z = xp[2];
      w.w = sqx[batchBase + j];
      stage4[pp] = w;
    }
    __syncthreads();
    const float4* st = stage4 + sub * 128;
    const unsigned T = Trow[r];
    for (int jj = 0; jj < 128; ++jj) {
      float4 w = st[jj];
      float dot = fmaf(xi2, w.z, fmaf(xi1, w.y, xi0 * w.x));
      float d = sqi + w.w - 2.0f * dot;
      unsigned key = fkey(d);
      if (key <= T) {
        int j = sub * 512 + round * 128 + jj;
        unsigned slot = atomicAdd(&cnt[r], 1u);
        if (slot < 40u) apb[r * 40 + slot] = ((u64)key << 16) | (unsigned)j;
      }
    }
  }
  __syncthreads();
  if (t < 32) {
    int n = (int)cnt[t]; if (n > 40) n = 40;
    u64 kk[32];
    #pragma unroll
    for (int q = 0; q < 32; ++q) kk[q] = ~0ULL;
    for (int i = 0; i < n; ++i) chain_insert<32>(kk, apb[t * 40 + i]);
    float sx = 0.f, sy = 0.f, sz = 0.f;
    #pragma unroll 4
    for (int z = 0; z < 32; ++z) {
      const float* xp = x + (size_t)(batchBase + (int)(kk[z] & 0xFFFFULL)) * 3;
      sx += xp[0]; sy += xp[1]; sz += xp[2];
    }
    const float m0 = sx * (1.f / 32.f), m1 = sy * (1.f / 32.f), m2 = sz * (1.f / 32.f);
    float c00 = 0, c01 = 0, c02 = 0, c11 = 0, c12 = 0, c22 = 0;
    #pragma unroll 4
    for (int z = 0; z < 32; ++z) {
      const float* xp = x + (size_t)(batchBase + (int)(kk[z] & 0xFFFFULL)) * 3;
      float a0 = xp[0] - m0, a1 = xp[1] - m1, a2 = xp[2] - m2;
      c00 = fmaf(a0, a0, c00); c01 = fmaf(a0, a1, c01); c02 = fmaf(a0, a2, c02);
      c11 = fmaf(a1, a1, c11); c12 = fmaf(a1, a2, c12); c22 = fmaf(a2, a2, c22);
    }
    const float inv = 1.f / 32.f;
    float* fp = feat + (size_t)(rowBase + t) * 12;
    fp[0] = xi0; fp[1] = xi1; fp[2] = xi2;
    fp[3] = c00 * inv; fp[4] = c01 * inv; fp[5] = c02 * inv;
    fp[6] = c01 * inv; fp[7] = c11 * inv; fp[8] = c12 * inv;
    fp[9] = c02 * inv; fp[10] = c12 * inv; fp[11] = c22 * inv;
  }
}

// ---------------- feat12 @ W1 -> y (+ per-block BN partials, deterministic) ----------------
__global__ __launch_bounds__(64) void mm12_64_kernel(const float* __restrict__ feat,
                                                     const float* __restrict__ W,
                                                     float* __restrict__ y,
                                                     float* __restrict__ psum,
                                                     float* __restrict__ psq) {
  __shared__ __align__(16) float Ws[12 * 64];
  const int t = threadIdx.x;
  for (int u = t; u < 192; u += 64) ((float4*)Ws)[u] = ((const float4*)W)[u];
  __syncthreads();
  const int row = blockIdx.x * 64 + t;
  float in[12];
  {
    const float4* fp = (const float4*)(feat + (size_t)row * 12);
    float4 a = fp[0], b = fp[1], c = fp[2];
    in[0] = a.x; in[1] = a.y; in[2] = a.z; in[3] = a.w;
    in[4] = b.x; in[5] = b.y; in[6] = b.z; in[7] = b.w;
    in[8] = c.x; in[9] = c.y; in[10] = c.z; in[11] = c.w;
  }
  float acc[64];
  #pragma unroll
  for (int o = 0; o < 64; ++o) acc[o] = 0.f;
  #pragma unroll
  for (int i = 0; i < 12; ++i) {
    const float xi = in[i];
    #pragma unroll
    for (int og = 0; og < 16; ++og) {
      float4 w4 = *(const float4*)(Ws + i * 64 + og * 4);
      acc[og * 4 + 0] = fmaf(xi, w4.x, acc[og * 4 + 0]);
      acc[og * 4 + 1] = fmaf(xi, w4.y, acc[og * 4 + 1]);
      acc[og * 4 + 2] = fmaf(xi, w4.z, acc[og * 4 + 2]);
      acc[og * 4 + 3] = fmaf(xi, w4.w, acc[og * 4 + 3]);
    }
  }
  float4* yp = (float4*)(y + (size_t)row * 64);
  #pragma unroll
  for (int og = 0; og < 16; ++og)
    yp[og] = make_float4(acc[og * 4 + 0], acc[og * 4 + 1], acc[og * 4 + 2], acc[og * 4 + 3]);
  #pragma unroll 1
  for (int o = 0; o < 64; ++o) {
    float s = acc[o], q = acc[o] * acc[o];
    #pragma unroll
    for (int m = 1; m < 64; m <<= 1) { s += __shfl_xor(s, m); q += __shfl_xor(q, m); }
    if (t == 0) { psum[blockIdx.x * 64 + o] = s; psq[blockIdx.x * 64 + o] = q; }
  }
}

// ---------------- generic 64->OUT matmul, optional fused BN+ReLU; per-block partials ----------------
template <int OUT, bool BNRELU>
__global__ __launch_bounds__(64) void mm64_kernel(const float* __restrict__ src,
                                                  const float* __restrict__ W,
                                                  const float* __restrict__ scale,
                                                  const float* __restrict__ shift,
                                                  float* __restrict__ y,
                                                  float* __restrict__ psum,
                                                  float* __restrict__ psq) {
  __shared__ __align__(16) float Ws[64 * OUT];
  const int t = threadIdx.x;
  for (int u = t; u < 16 * OUT; u += 64) ((float4*)Ws)[u] = ((const float4*)W)[u];
  __syncthreads();
  const int row = blockIdx.x * 64 + t;
  float in[64];
  {
    const float4* sp = (const float4*)(src + (size_t)row * 64);
    #pragma unroll
    for (int u = 0; u < 16; ++u) {
      float4 v = sp[u];
      if (BNRELU) {
        v.x = fmaxf(fmaf(v.x, scale[u * 4 + 0], shift[u * 4 + 0]), 0.f);
        v.y = fmaxf(fmaf(v.y, scale[u * 4 + 1], shift[u * 4 + 1]), 0.f);
        v.z = fmaxf(fmaf(v.z, scale[u * 4 + 2], shift[u * 4 + 2]), 0.f);
        v.w = fmaxf(fmaf(v.w, scale[u * 4 + 3], shift[u * 4 + 3]), 0.f);
      }
      in[u * 4 + 0] = v.x; in[u * 4 + 1] = v.y; in[u * 4 + 2] = v.z; in[u * 4 + 3] = v.w;
    }
  }
  for (int half = 0; half < OUT / 64; ++half) {
    float acc[64];
    #pragma unroll
    for (int o = 0; o < 64; ++o) acc[o] = 0.f;
    #pragma unroll 4
    for (int i = 0; i < 64; ++i) {
      const float xi = in[i];
      #pragma unroll
      for (int og = 0; og < 16; ++og) {
        float4 w4 = *(const float4*)(Ws + i * OUT + half * 64 + og * 4);
        acc[og * 4 + 0] = fmaf(xi, w4.x, acc[og * 4 + 0]);
        acc[og * 4 + 1] = fmaf(xi, w4.y, acc[og * 4 + 1]);
        acc[og * 4 + 2] = fmaf(xi, w4.z, acc[og * 4 + 2]);
        acc[og * 4 + 3] = fmaf(xi, w4.w, acc[og * 4 + 3]);
      }
    }
    float4* yp = (float4*)(y + (size_t)row * OUT + half * 64);
    #pragma unroll
    for (int og = 0; og < 16; ++og)
      yp[og] = make_float4(acc[og * 4 + 0], acc[og * 4 + 1], acc[og * 4 + 2], acc[og * 4 + 3]);
    #pragma unroll 1
    for (int o = 0; o < 64; ++o) {
      float s = acc[o], q = acc[o] * acc[o];
      #pragma unroll
      for (int m = 1; m < 64; m <<= 1) { s += __shfl_xor(s, m); q += __shfl_xor(q, m); }
      if (t == 0) {
        psum[blockIdx.x * OUT + half * 64 + o] = s;
        psq[blockIdx.x * OUT + half * 64 + o] = q;
      }
    }
  }
}

// ---------------- deterministic BN finalize from 256 per-block partials ----------------
template <int C>
__global__ void finP_kernel(const float* __restrict__ psum, const float* __restrict__ psq,
                            const float* __restrict__ g, const float* __restrict__ b,
                            float* __restrict__ scale, float* __restrict__ shift) {
  int c = threadIdx.x;
  float s = 0.f, q = 0.f;
  for (int bb = 0; bb < 256; ++bb) { s += psum[bb * C + c]; q += psq[bb * C + c]; }
  float m = s * (1.f / 16384.f);
  float v = q * (1.f / 16384.f) - m * m;
  float sc = g[c] * rsqrtf(v + 1e-5f);
  scale[c] = sc;
  shift[c] = b[c] - m * sc;
}

// ---------------- apply BN + activation, compute row sq-norm ----------------
template <int C, bool LEAKY>
__global__ __launch_bounds__(256) void apply_kernel(const float* __restrict__ yraw,
                                                    const float* __restrict__ scale,
                                                    const float* __restrict__ shift,
                                                    float* __restrict__ hout,
                                                    float* __restrict__ sqout) {
  const int row = blockIdx.x * 256 + threadIdx.x;
  const float4* sp = (const float4*)(yraw + (size_t)row * C);
  float4* dp = (float4*)(hout + (size_t)row * C);
  float sq = 0.f;
  #pragma unroll
  for (int u = 0; u < C / 4; ++u) {
    float4 v = sp[u];
    float4 o;
    o.x = fmaf(v.x, scale[u * 4 + 0], shift[u * 4 + 0]);
    o.y = fmaf(v.y, scale[u * 4 + 1], shift[u * 4 + 1]);
    o.z = fmaf(v.z, scale[u * 4 + 2], shift[u * 4 + 2]);
    o.w = fmaf(v.w, scale[u * 4 + 3], shift[u * 4 + 3]);
    if (LEAKY) {
      o.x = o.x > 0.f ? o.x : 0.01f * o.x;
      o.y = o.y > 0.f ? o.y : 0.01f * o.y;
      o.z = o.z > 0.f ? o.z : 0.01f * o.z;
      o.w = o.w > 0.f ? o.w : 0.01f * o.w;
    } else {
      o.x = fmaxf(o.x, 0.f); o.y = fmaxf(o.y, 0.f);
      o.z = fmaxf(o.z, 0.f); o.w = fmaxf(o.w, 0.f);
    }
    sq = fmaf(o.x, o.x, sq); sq = fmaf(o.y, o.y, sq);
    sq = fmaf(o.z, o.z, sq); sq = fmaf(o.w, o.w, sq);
    dp[u] = o;
  }
  sqout[row] = sq;
}

// ---------------- knn(k=8): distance GEMM + register top-8 -> per-(row,quarter) lists ----
// 256 thr (16x16), 64 rows/block, 4x4 micro-tile; B staged in 64-k chunks.
// grid = 256 rowGroups x 4 col-quarters (2048 cols each).
template <int C>
__global__ __launch_bounds__(256, 4) void knn8_kernel(const float* __restrict__ h,
                                                      const float* __restrict__ sqh,
                                                      u64* __restrict__ plist) {
  static_assert(C == 64 || C == 128, "C");
  constexpr int SMEMB = (C * 64 * 4 + 64 * 64 * 4) > 32768 ? (C * 64 * 4 + 64 * 64 * 4) : 32768;
  __shared__ __align__(16) unsigned char smem[SMEMB];
  float* As = (float*)smem;                   // [C][64]
  float* Bs = (float*)(smem + C * 64 * 4);    // [64][64] per chunk
  __shared__ float sqAs[64];
  __shared__ float sqBs[64];
  u64* mb = (u64*)smem;                        // merge buf [32][16][8] (32KB), after scan

  const int t = threadIdx.x;
  const int rg = blockIdx.x >> 2, quarter = blockIdx.x & 3;
  const int rowBase = rg * 64;
  const int batchBase = rowBase & ~(NPTS - 1);
  const int tx = t & 15, ty = t >> 4;

  // stage A (full C, transposed to [k][row])
  {
    const int ar = t & 63;
    const int k0 = (t >> 6) * (C / 4);
    const float* src = h + (size_t)(rowBase + ar) * C + k0;
    #pragma unroll
    for (int kk = 0; kk < C / 4; kk += 4) {
      float4 v = *(const float4*)(src + kk);
      As[(k0 + kk + 0) * 64 + ar] = v.x;
      As[(k0 + kk + 1) * 64 + ar] = v.y;
      As[(k0 + kk + 2) * 64 + ar] = v.z;
      As[(k0 + kk + 3) * 64 + ar] = v.w;
    }
    if (t < 64) sqAs[t] = sqh[rowBase + t];
  }

  u64 L[4][8];
  #pragma unroll
  for (int q = 0; q < 4; ++q)
    #pragma unroll
    for (int z = 0; z < 8; ++z) L[q][z] = ~0ULL;

  for (int tile = 0; tile < 32; ++tile) {
    const int colBase = quarter * 2048 + tile * 64;
    float acc[16];
    #pragma unroll
    for (int q = 0; q < 16; ++q) acc[q] = 0.f;
    for (int ch = 0; ch < C / 64; ++ch) {
      __syncthreads();
      {
        const int bc = t & 63;
        const int k0 = (t >> 6) * 16;
        const float* src = h + (size_t)(batchBase + colBase + bc) * C + ch * 64 + k0;
        #pragma unroll
        for (int kk = 0; kk < 16; kk += 4) {
          float4 v = *(const float4*)(src + kk);
          Bs[(k0 + kk + 0) * 64 + bc] = v.x;
          Bs[(k0 + kk + 1) * 64 + bc] = v.y;
          Bs[(k0 + kk + 2) * 64 + bc] = v.z;
          Bs[(k0 + kk + 3) * 64 + bc] = v.w;
        }
        if (ch == 0 && t < 64) sqBs[t] = sqh[batchBase + colBase + t];
      }
      __syncthreads();
      const float* Ab = As + ch * 64 * 64;
      #pragma unroll 4
      for (int k = 0; k < 64; ++k) {
        float4 a4 = *(const float4*)(Ab + k * 64 + ty * 4);
        float4 b4 = *(const float4*)(Bs + k * 64 + tx * 4);
        acc[0] = fmaf(a4.x, b4.x, acc[0]);   acc[1] = fmaf(a4.x, b4.y, acc[1]);
        acc[2] = fmaf(a4.x, b4.z, acc[2]);   acc[3] = fmaf(a4.x, b4.w, acc[3]);
        acc[4] = fmaf(a4.y, b4.x, acc[4]);   acc[5] = fmaf(a4.y, b4.y, acc[5]);
        acc[6] = fmaf(a4.y, b4.z, acc[6]);   acc[7] = fmaf(a4.y, b4.w, acc[7]);
        acc[8] = fmaf(a4.z, b4.x, acc[8]);   acc[9] = fmaf(a4.z, b4.y, acc[9]);
        acc[10] = fmaf(a4.z, b4.z, acc[10]); acc[11] = fmaf(a4.z, b4.w, acc[11]);
        acc[12] = fmaf(a4.w, b4.x, acc[12]); acc[13] = fmaf(a4.w, b4.y, acc[13]);
        acc[14] = fmaf(a4.w, b4.z, acc[14]); acc[15] = fmaf(a4.w, b4.w, acc[15]);
      }
    }
    #pragma unroll
    for (int q = 0; q < 4; ++q) {
      const float sa = sqAs[ty * 4 + q];
      #pragma unroll
      for (int p = 0; p < 4; ++p) {
        float d = sa + sqBs[tx * 4 + p] - 2.0f * acc[q * 4 + p];
        int j = colBase + tx * 4 + p;
        u64 key = ((u64)fkey(d) << 16) | (unsigned)j;
        chain_insert<8>(L[q], key);
      }
    }
  }
  // merge in two 32-row passes (mb aliases staging)
  for (int rh = 0; rh < 2; ++rh) {
    __syncthreads();
    if (ty >= rh * 8 && ty < rh * 8 + 8) {
      #pragma unroll
      for (int q = 0; q < 4; ++q) {
        int lr = (ty - rh * 8) * 4 + q;     // 0..31
        #pragma unroll
        for (int z = 0; z < 8; ++z) mb[(lr * 16 + tx) * 8 + z] = L[q][z];
      }
    }
    __syncthreads();
    if (t < 32) {
      int ps[16];
      #pragma unroll
      for (int s = 0; s < 16; ++s) ps[s] = 0;
      u64 outk[8];
      for (int z = 0; z < 8; ++z) {
        u64 best = ~0ULL; int bs = 0;
        #pragma unroll
        for (int s = 0; s < 16; ++s) {
          u64 v = mb[(t * 16 + s) * 8 + ps[s]];
          if (v < best) { best = v; bs = s; }
        }
        outk[z] = best;
        #pragma unroll
        for (int s = 0; s < 16; ++s) ps[s] += (s == bs);
      }
      u64* dst = plist + ((size_t)(rowBase + rh * 32 + t) * 4 + quarter) * 8;
      #pragma unroll
      for (int z = 0; z < 8; ++z) dst[z] = outk[z];
    }
  }
}

// ---------------- merge 4 quarter-lists -> top-8 idx; fused gather-max ----------------
// block 256 = 4 rows x 64 lanes
template <int C>
__global__ __launch_bounds__(256) void knn8mg_kernel(const u64* __restrict__ plist,
                                                     const float* __restrict__ h,
                                                     float* __restrict__ nout) {
  const int row = blockIdx.x * 4 + (threadIdx.x >> 6);
  const int lane = threadIdx.x & 63;
  const int batchBase = row & ~(NPTS - 1);
  const u64* A = plist + (size_t)row * 32;
  u64 kk[8];
  #pragma unroll
  for (int z = 0; z < 8; ++z) kk[z] = A[z];
  #pragma unroll
  for (int z = 8; z < 32; ++z) chain_insert<8>(kk, A[z]);
  constexpr int PER = C / 64;
  float mx[PER];
  #pragma unroll
  for (int u = 0; u < PER; ++u) mx[u] = -FLT_MAX;
  #pragma unroll
  for (int z = 0; z < 8; ++z) {
    int idx = (int)(kk[z] & 0xFFFFULL);
    const float* src = h + (size_t)(batchBase + idx) * C;
    #pragma unroll
    for (int u = 0; u < PER; ++u)
      mx[u] = fmaxf(mx[u], src[lane + u * 64]);
  }
  float* dst = nout + (size_t)row * C;
  #pragma unroll
  for (int u = 0; u < PER; ++u) dst[lane + u * 64] = mx[u];
}

// ---------------- n2[16384,128] @ gW2[128,1024]: deterministic stats partials + atomicMax ----------------
__global__ __launch_bounds__(256) void mmE_kernel(const float* __restrict__ n2,
                                                  const float* __restrict__ W,
                                                  float* __restrict__ psum,
                                                  float* __restrict__ psq,
                                                  unsigned* __restrict__ gmax) {
  __shared__ __align__(16) float As[64 * 64];
  __shared__ __align__(16) float Bs[64 * 64];
  __shared__ float sP[16 * 64];
  __shared__ float qP[16 * 64];
  __shared__ float mP[16 * 64];
  const int t = threadIdx.x;
  const int rowStripe = blockIdx.x >> 4;
  const int colStripe = blockIdx.x & 15;
  const int rowBase = rowStripe * 64;
  const int colBase = colStripe * 64;
  const int batch = rowBase >> 13;
  const int tx = t & 15, ty = t >> 4;

  float acc[16];
  #pragma unroll
  for (int q = 0; q < 16; ++q) acc[q] = 0.f;

  for (int kh = 0; kh < 2; ++kh) {
    __syncthreads();
    {
      const int ar = t & 63;
      const int k0 = (t >> 6) * 16;
      const float* src = n2 + (size_t)(rowBase + ar) * 128 + kh * 64 + k0;
      #pragma unroll
      for (int kk = 0; kk < 16; kk += 4) {
        float4 v = *(const float4*)(src + kk);
        As[(k0 + kk + 0) * 64 + ar] = v.x;
        As[(k0 + kk + 1) * 64 + ar] = v.y;
        As[(k0 + kk + 2) * 64 + ar] = v.z;
        As[(k0 + kk + 3) * 64 + ar] = v.w;
      }
    }
    {
      #pragma unroll
      for (int z = 0; z < 4; ++z) {
        int u = t + 256 * z;
        int k = u >> 4, c4 = u & 15;
        float4 v = *(const float4*)(W + (size_t)(kh * 64 + k) * 1024 + colBase + c4 * 4);
        *(float4*)(Bs + k * 64 + c4 * 4) = v;
      }
    }
    __syncthreads();
    #pragma unroll 4
    for (int k = 0; k < 64; ++k) {
      float4 a4 = *(const float4*)(As + k * 64 + ty * 4);
      float4 b4 = *(const float4*)(Bs + k * 64 + tx * 4);
      acc[0] = fmaf(a4.x, b4.x, acc[0]);   acc[1] = fmaf(a4.x, b4.y, acc[1]);
      acc[2] = fmaf(a4.x, b4.z, acc[2]);   acc[3] = fmaf(a4.x, b4.w, acc[3]);
      acc[4] = fmaf(a4.y, b4.x, acc[4]);   acc[5] = fmaf(a4.y, b4.y, acc[5]);
      acc[6] = fmaf(a4.y, b4.z, acc[6]);   acc[7] = fmaf(a4.y, b4.w, acc[7]);
      acc[8] = fmaf(a4.z, b4.x, acc[8]);   acc[9] = fmaf(a4.z, b4.y, acc[9]);
      acc[10] = fmaf(a4.z, b4.z, acc[10]); acc[11] = fmaf(a4.z, b4.w, acc[11]);
      acc[12] = fmaf(a4.w, b4.x, acc[12]); acc[13] = fmaf(a4.w, b4.y, acc[13]);
      acc[14] = fmaf(a4.w, b4.z, acc[14]); acc[15] = fmaf(a4.w, b4.w, acc[15]);
    }
  }
  #pragma unroll
  for (int p = 0; p < 4; ++p) {
    float s = 0.f, q = 0.f, m = -FLT_MAX;
    #pragma unroll
    for (int qq = 0; qq < 4; ++qq) {
      float v = acc[qq * 4 + p];
      s += v; q = fmaf(v, v, q); m = fmaxf(m, v);
    }
    sP[ty * 64 + tx * 4 + p] = s;
    qP[ty * 64 + tx * 4 + p] = q;
    mP[ty * 64 + tx * 4 + p] = m;
  }
  __syncthreads();
  if (t < 64) {
    float s = 0.f, q = 0.f, m = -FLT_MAX;
    #pragma unroll
    for (int u = 0; u < 16; ++u) {
      s += sP[u * 64 + t];
      q += qP[u * 64 + t];
      m = fmaxf(m, mP[u * 64 + t]);
    }
    psum[rowStripe * 1024 + colBase + t] = s;
    psq [rowStripe * 1024 + colBase + t] = q;
    atomicMax(&gmax[batch * 1024 + colBase + t], fkey(m));
  }
}

// ---------------- BN4 finalize (deterministic stripe sum) + leaky on pooled max ----------------
__global__ void poolbn_kernel(const float* __restrict__ psumE, const float* __restrict__ psqE,
                              const unsigned* __restrict__ gmax,
                              const float* __restrict__ gg2, const float* __restrict__ gb2,
                              float* __restrict__ fpool) {
  int c = threadIdx.x;
  float s = 0.f, q = 0.f;
  for (int bb = 0; bb < 256; ++bb) { s += psumE[bb * 1024 + c]; q += psqE[bb * 1024 + c]; }
  float m = s * (1.f / 16384.f);
  float v = q * (1.f / 16384.f) - m * m;
  float sc = gg2[c] * rsqrtf(v + 1e-5f);
  float sh = gb2[c] - m * sc;
  #pragma unroll
  for (int b = 0; b < 2; ++b) {
    float raw = fdecode(gmax[b * 1024 + c]);
    float t = fmaf(raw, sc, sh);
    fpool[b * 1024 + c] = t > 0.f ? t : 0.01f * t;
  }
}

// ---------------- fpool @ W4 + BN over 2 samples + relu -> out ----------------
__global__ __launch_bounds__(64) void final_kernel(const float* __restrict__ fpool,
                                                   const float* __restrict__ W4,
                                                   const float* __restrict__ g4,
                                                   const float* __restrict__ b4f,
                                                   float* __restrict__ out) {
  const int o = blockIdx.x * 64 + threadIdx.x;
  float a0 = 0.f, a1 = 0.f;
  for (int c = 0; c < 1024; ++c) {
    float w = W4[(size_t)c * 512 + o];
    a0 = fmaf(fpool[c], w, a0);
    a1 = fmaf(fpool[1024 + c], w, a1);
  }
  float m = 0.5f * (a0 + a1);
  float d0 = a0 - m, d1 = a1 - m;
  float v = 0.5f * (d0 * d0 + d1 * d1);
  float r = rsqrtf(v + 1e-5f);
  float o0 = fmaf(d0 * r, g4[o], b4f[o]);
  float o1 = fmaf(d1 * r, g4[o], b4f[o]);
  out[o] = fmaxf(o0, 0.f);
  out[512 + o] = fmaxf(o1, 0.f);
}

extern "C" void kernel_launch(void* const* d_in, const int* in_sizes, int n_in,
                              void* d_out, int out_size, void* d_ws, size_t ws_size,
                              hipStream_t stream) {
  (void)in_sizes; (void)n_in; (void)out_size; (void)ws_size;
  const float* x   = (const float*)d_in[0];
  const float* W1  = (const float*)d_in[1];
  const float* g1  = (const float*)d_in[2];
  const float* b1  = (const float*)d_in[3];
  const float* W2  = (const float*)d_in[4];
  const float* g2  = (const float*)d_in[5];
  const float* b2  = (const float*)d_in[6];
  const float* W3  = (const float*)d_in[7];
  const float* g3  = (const float*)d_in[8];
  const float* b3  = (const float*)d_in[9];
  const float* gW1 = (const float*)d_in[10];
  const float* gg1 = (const float*)d_in[11];
  const float* gb1 = (const float*)d_in[12];
  const float* gW2 = (const float*)d_in[13];
  const float* gg2 = (const float*)d_in[14];
  const float* gb2 = (const float*)d_in[15];
  const float* W4  = (const float*)d_in[16];
  const float* g4  = (const float*)d_in[17];
  const float* b4  = (const float*)d_in[18];
  float* out = (float*)d_out;
  float* ws = (float*)d_ws;

  float* sqx  = ws;                  // 16384
  float* feat = sqx + 16384;         // 196608
  float* yA   = feat + 196608;       // 1048576
  float* yB   = yA + 1048576;        // 1048576
  float* h3   = yB + 1048576;        // 1048576
  float* sqh  = h3 + 1048576;        // 16384
  float* yg1  = sqh + 16384;         // 2097152
  float* hg1  = yg1 + 2097152;       // 2097152
  float* sqg  = hg1 + 2097152;       // 16384
  float* st   = sqg + 16384;         // stats / small buffers

  unsigned* gmax = (unsigned*)(st);          // 2048 uints
  float* scale0 = st + 2048;  float* shift0 = st + 2112;
  float* scale1 = st + 2176;  float* shift1 = st + 2240;
  float* scale2 = st + 2304;  float* shift2 = st + 2368;
  float* scale3 = st + 2432;  float* shift3 = st + 2560;
  float* fpool  = st + 2688;                 // 2048
  float* p1s    = st + 4736;                 // 256*64
  float* p1q    = p1s + 16384;               // 256*64

  // partials / lists aliased into dead buffers:
  float* p2s = feat;             float* p2q = feat + 16384;        // L2 stats
  float* p3s = feat + 32768;     float* p3q = feat + 49152;        // L3 stats
  float* p4s = yB;               float* p4q = yB + 32768;          // gW1 stats
  float* pEs = h3;               float* pEq = h3 + 262144;         // mmE stats
  u64* plist = (u64*)yB;                                           // knn8 lists (4MB)

  float* n1 = yA;   // raw y3 consumed by apply before knn8mg writes here
  float* n2 = yg1;  // raw yg1 consumed by apply before knn8mg writes here

  hipMemsetAsync(gmax, 0, 2048 * sizeof(unsigned), stream);
  sqx_kernel<<<64, 256, 0, stream>>>(x, sqx);
  knn32_cov_kernel<<<512, 512, 0, stream>>>(x, sqx, feat);
  mm12_64_kernel<<<256, 64, 0, stream>>>(feat, W1, yA, p1s, p1q);
  finP_kernel<64><<<1, 64, 0, stream>>>(p1s, p1q, g1, b1, scale0, shift0);
  mm64_kernel<64, true><<<256, 64, 0, stream>>>(yA, W2, scale0, shift0, yB, p2s, p2q);
  finP_kernel<64><<<1, 64, 0, stream>>>(p2s, p2q, g2, b2, scale1, shift1);
  mm64_kernel<64, true><<<256, 64, 0, stream>>>(yB, W3, scale1, shift1, yA, p3s, p3q);
  finP_kernel<64><<<1, 64, 0, stream>>>(p3s, p3q, g3, b3, scale2, shift2);
  apply_kernel<64, false><<<64, 256, 0, stream>>>(yA, scale2, shift2, h3, sqh);
  knn8_kernel<64><<<1024, 256, 0, stream>>>(h3, sqh, plist);
  knn8mg_kernel<64><<<4096, 256, 0, stream>>>(plist, h3, n1);
  mm64_kernel<128, false><<<256, 64, 0, stream>>>(n1, gW1, scale0, shift0, yg1, p4s, p4q);
  finP_kernel<128><<<1, 128, 0, stream>>>(p4s, p4q, gg1, gb1, scale3, shift3);
  apply_kernel<128, true><<<64, 256, 0, stream>>>(yg1, scale3, shift3, hg1, sqg);
  knn8_kernel<128><<<1024, 256, 0, stream>>>(hg1, sqg, plist);
  knn8mg_kernel<128><<<4096, 256, 0, stream>>>(plist, hg1, n2);
  mmE_kernel<<<4096, 256, 0, stream>>>(n2, gW2, pEs, pEq, gmax);
  poolbn_kernel<<<1, 1024, 0, stream>>>(pEs, pEq, gmax, gg2, gb2, fpool);
  final_kernel<<<8, 64, 0, stream>>>(fpool, W4, g4, b4, out);
}